// Round 7
// baseline (411.189 us; speedup 1.0000x reference)
//
#include <hip/hip_runtime.h>
#include <hip/hip_bf16.h>
#include <math.h>

#define DEVI static __device__ __forceinline__

typedef __attribute__((ext_vector_type(4))) float f32x4;
typedef __attribute__((ext_vector_type(16))) float f32x16;
typedef __attribute__((ext_vector_type(8))) short bf16x8;
typedef __attribute__((ext_vector_type(4))) short bf16x4;

constexpr int Bc = 4, Lc = 2048, Sc = 2048, Dc = 1024, Hc = 8, Ec = 128, UVc = 128;
constexpr int HEc = Hc * Ec;   // 1024
constexpr int BLc = Bc * Lc;   // 8192

// scale * log2(e): folded into q so exp(scale*qk) == exp2(d)
#define QSC (1.44269504088896340f / 11.31370849898476039f)

DEVI unsigned f2bf_bits(float f) {
  unsigned u = __builtin_bit_cast(unsigned, f);
  return (u + 0x7FFFu + ((u >> 16) & 1u)) >> 16;
}
DEVI short f2bf(float f) { return (short)f2bf_bits(f); }
DEVI float bf2f(short s) {
  return __builtin_bit_cast(float, (unsigned)((unsigned short)s) << 16);
}
DEVI float gelu_f(float x) { return 0.5f * x * (1.0f + erff(x * 0.7071067811865476f)); }

DEVI void gload16(const void* gsrc, void* ldst) {
  __builtin_amdgcn_global_load_lds(
      (const __attribute__((address_space(1))) unsigned*)gsrc,
      (__attribute__((address_space(3))) unsigned*)(ldst), 16, 0, 0);
}

DEVI f32x4 mfma16(bf16x8 a, bf16x8 b, f32x4 c) {
  return __builtin_amdgcn_mfma_f32_16x16x32_bf16(a, b, c, 0, 0, 0);
}
DEVI f32x16 mfma32(bf16x8 a, bf16x8 b, f32x16 c) {
  return __builtin_amdgcn_mfma_f32_32x32x16_bf16(a, b, c, 0, 0, 0);
}

// ---------------- prep: f32 -> bf16 convert, 3 tensors in one launch ----------------
__global__ void cvt3_kernel(const float* __restrict__ i0, const float* __restrict__ i1,
                            const float* __restrict__ i2, short* __restrict__ o0,
                            short* __restrict__ o1, short* __restrict__ o2) {
  const float* ins[3] = {i0, i1, i2};
  short* outs[3] = {o0, o1, o2};
  const float* in = ins[blockIdx.y];
  short* out = outs[blockIdx.y];
  size_t i = ((size_t)blockIdx.x * 256 + threadIdx.x) * 8;
  float4 f1 = *reinterpret_cast<const float4*>(in + i);
  float4 f2 = *reinterpret_cast<const float4*>(in + i + 4);
  uint4 pk;
  pk.x = f2bf_bits(f1.x) | (f2bf_bits(f1.y) << 16);
  pk.y = f2bf_bits(f1.z) | (f2bf_bits(f1.w) << 16);
  pk.z = f2bf_bits(f2.x) | (f2bf_bits(f2.y) << 16);
  pk.w = f2bf_bits(f2.z) | (f2bf_bits(f2.w) << 16);
  *reinterpret_cast<uint4*>(out + i) = pk;
}

// ---------------- prep: 4 weight transposes f32[K][N] -> bf16 WT[N][K] ----------------
__global__ void wt_trans_kernel(const float* __restrict__ W0, const float* __restrict__ W1,
                                const float* __restrict__ W2, const float* __restrict__ W3,
                                short* __restrict__ T0, short* __restrict__ T1,
                                short* __restrict__ T2, short* __restrict__ T3) {
  __shared__ float t[32][33];
  const float* Ws[4] = {W0, W1, W2, W3};
  short* Ts[4] = {T0, T1, T2, T3};
  const float* W = Ws[blockIdx.z];
  short* WT = Ts[blockIdx.z];
  int tx = threadIdx.x, ty = threadIdx.y;
  int n0 = blockIdx.x * 32, k0 = blockIdx.y * 32;
#pragma unroll
  for (int i = 0; i < 4; i++) {
    int r = ty + i * 8;
    t[r][tx] = W[(size_t)(k0 + r) * 1024 + n0 + tx];
  }
  __syncthreads();
#pragma unroll
  for (int i = 0; i < 4; i++) {
    int r = ty + i * 8;
    WT[(size_t)(n0 + r) * 1024 + k0 + tx] = f2bf(t[tx][r]);
  }
}

// ---------------- prep: packed rope table [2048][512] of (cos,sin) ----------------
__global__ void rope_cs_kernel(float2* __restrict__ cs) {
  int idx = blockIdx.x * 256 + threadIdx.x;  // 1M
  int t = idx >> 9, i = idx & 511;
  float inv = expf((float)i * (-9.210340371976184f / 512.0f));  // 10000^(-i/512)
  float sv, cv;
  sincosf((float)t * inv, &sv, &cv);
  cs[idx] = make_float2(cv, sv);
}

// ---------------- GEMM: C = epi(A @ W + bias); A bf16 [M][K], W as WT[N][K] bf16 ----------
// 128x128 tile, BK=32, 3-buffer LDS pipeline (counted vmcnt, 1 barrier/step).
// EPI: 0 = f32+bias, 1 = gelu->bf16, 3 = gelu->bf16 written transposed to vT layout.
template <int EPI>
__global__ __launch_bounds__(256, 3) void gemm_kernel(
    const short* __restrict__ A, const short* __restrict__ BT,
    const float* __restrict__ bias, void* __restrict__ Cptr, int M, int N, int K) {
  __shared__ char smem[49152];  // A bufs 3x8K @0, B bufs 3x8K @24K
  const int tid = threadIdx.x;
  const int wave = tid >> 6, lane = tid & 63;
  const int lquad = lane >> 4, l15 = lane & 15;
  const int m0 = blockIdx.x * 128, n0 = blockIdx.y * 128;
  const int wr = wave >> 1, wc = wave & 1;
  f32x4 acc[4][4] = {};

  const int q0 = tid * 16, q1 = tid * 16 + 4096;
  const int r0 = q0 >> 6, o0 = (q0 & 63) ^ ((r0 & 3) << 4);
  const int r1 = q1 >> 6, o1 = (q1 & 63) ^ ((r1 & 3) << 4);
  const short* a0 = A + (size_t)(m0 + r0) * K + (o0 >> 1);
  const short* a1 = A + (size_t)(m0 + r1) * K + (o1 >> 1);
  const short* b0 = BT + (size_t)(n0 + r0) * K + (o0 >> 1);
  const short* b1 = BT + (size_t)(n0 + r1) * K + (o1 >> 1);

#define G_STAGE(buf, kt)                     \
  {                                          \
    char* As_ = smem + (buf)*8192;           \
    char* Bs_ = smem + 24576 + (buf)*8192;   \
    gload16(a0 + (kt), As_ + q0);            \
    gload16(a1 + (kt), As_ + q1);            \
    gload16(b0 + (kt), Bs_ + q0);            \
    gload16(b1 + (kt), Bs_ + q1);            \
  }

  G_STAGE(0, 0);
  G_STAGE(1, 32);
  asm volatile("s_waitcnt vmcnt(4)" ::: "memory");
  __builtin_amdgcn_s_barrier();

  const int NT = K >> 5;
  int cur = 0;
  for (int t = 0; t < NT; t++) {
    int nb = cur + 2;
    if (nb >= 3) nb -= 3;
    G_STAGE(nb, (t + 2 < NT) ? (t + 2) * 32 : 0);  // dummy tail keeps vmcnt math uniform
    __builtin_amdgcn_sched_barrier(0);
    const char* As_ = smem + cur * 8192;
    const char* Bs_ = smem + 24576 + cur * 8192;
    const int ko = lquad * 16;
    bf16x8 a[4], b[4];
#pragma unroll
    for (int f = 0; f < 4; f++) {
      int ra = wr * 64 + f * 16 + l15;
      a[f] = *reinterpret_cast<const bf16x8*>(As_ + ra * 64 + (ko ^ ((ra & 3) << 4)));
      int rb = wc * 64 + f * 16 + l15;
      b[f] = *reinterpret_cast<const bf16x8*>(Bs_ + rb * 64 + (ko ^ ((rb & 3) << 4)));
    }
#pragma unroll
    for (int mf = 0; mf < 4; mf++)
#pragma unroll
      for (int nf = 0; nf < 4; nf++)
        acc[mf][nf] = mfma16(a[mf], b[nf], acc[mf][nf]);
    asm volatile("s_waitcnt vmcnt(4) lgkmcnt(0)" ::: "memory");
    __builtin_amdgcn_sched_barrier(0);
    __builtin_amdgcn_s_barrier();
    cur = (cur == 2) ? 0 : cur + 1;
  }
#undef G_STAGE

#pragma unroll
  for (int mf = 0; mf < 4; mf++) {
#pragma unroll
    for (int nf = 0; nf < 4; nf++) {
      const int mrow = m0 + wr * 64 + mf * 16 + 4 * lquad;
      const int ncol = n0 + wc * 64 + nf * 16 + l15;
      const float bval = bias[ncol];
      if constexpr (EPI == 3) {
        // transposed V write: vT[((b*8+h)*128+d)*2048 + s], s = 4 consecutive (over r)
        int hh = ncol >> 7, dd = ncol & 127;
        int bb = mrow >> 11, ss = mrow & 2047;
        bf16x4 gv;
#pragma unroll
        for (int r = 0; r < 4; r++) gv[r] = f2bf(gelu_f(acc[mf][nf][r] + bval));
        *reinterpret_cast<bf16x4*>((short*)Cptr + (((size_t)bb * 8 + hh) * 128 + dd) * 2048 + ss) = gv;
      } else if constexpr (EPI == 1) {
#pragma unroll
        for (int r = 0; r < 4; r++)
          ((short*)Cptr)[(size_t)(mrow + r) * N + ncol] = f2bf(gelu_f(acc[mf][nf][r] + bval));
      } else {
#pragma unroll
        for (int r = 0; r < 4; r++)
          ((float*)Cptr)[(size_t)(mrow + r) * N + ncol] = acc[mf][nf][r] + bval;
      }
    }
  }
}

// ---------------- rope apply: qk_gelu -> q (pre-scaled by QSC), k ----------------
__global__ void rope_apply_kernel(const short* __restrict__ qkg,
                                  const float2* __restrict__ cstab,
                                  const float* __restrict__ qg, const float* __restrict__ qb,
                                  const float* __restrict__ kg, const float* __restrict__ kb,
                                  short* __restrict__ qo, short* __restrict__ ko) {
  int tid = blockIdx.x * 256 + threadIdx.x;
  size_t base = (size_t)tid * 8;
  int bl = (int)(base >> 10);
  int rem = (int)(base & 1023);
  int e0 = rem & 127;
  int t = bl & 2047;
  int pf = rem >> 1;  // flat pair index
  uint4 raw = *reinterpret_cast<const uint4*>(qkg + base);
  short sh[8];
  *reinterpret_cast<uint4*>(sh) = raw;
  const float* csf = (const float*)cstab + (size_t)t * 1024 + 2 * pf;
  float4 p01 = *reinterpret_cast<const float4*>(csf);
  float4 p23 = *reinterpret_cast<const float4*>(csf + 4);
  float C[4] = {p01.x, p01.z, p23.x, p23.z};
  float Sn[4] = {p01.y, p01.w, p23.y, p23.w};
  float4 qga = *reinterpret_cast<const float4*>(qg + e0);
  float4 qgb = *reinterpret_cast<const float4*>(qg + e0 + 4);
  float4 qba = *reinterpret_cast<const float4*>(qb + e0);
  float4 qbb = *reinterpret_cast<const float4*>(qb + e0 + 4);
  float4 kga = *reinterpret_cast<const float4*>(kg + e0);
  float4 kgb = *reinterpret_cast<const float4*>(kg + e0 + 4);
  float4 kba = *reinterpret_cast<const float4*>(kb + e0);
  float4 kbb = *reinterpret_cast<const float4*>(kb + e0 + 4);
  float QG[8] = {qga.x, qga.y, qga.z, qga.w, qgb.x, qgb.y, qgb.z, qgb.w};
  float QB[8] = {qba.x, qba.y, qba.z, qba.w, qbb.x, qbb.y, qbb.z, qbb.w};
  float KG[8] = {kga.x, kga.y, kga.z, kga.w, kgb.x, kgb.y, kgb.z, kgb.w};
  float KB[8] = {kba.x, kba.y, kba.z, kba.w, kbb.x, kbb.y, kbb.z, kbb.w};
  short qsh[8], ksh[8];
#pragma unroll
  for (int j = 0; j < 4; j++) {
    float x0 = bf2f(sh[2 * j]), x1 = bf2f(sh[2 * j + 1]);
    float q0 = x0 * QG[2 * j] + QB[2 * j];
    float q1 = x1 * QG[2 * j + 1] + QB[2 * j + 1];
    qsh[2 * j] = f2bf((q0 * C[j] - q1 * Sn[j]) * QSC);
    qsh[2 * j + 1] = f2bf((q1 * C[j] + q0 * Sn[j]) * QSC);
    float k0v = x0 * KG[2 * j] + KB[2 * j];
    float k1v = x1 * KG[2 * j + 1] + KB[2 * j + 1];
    ksh[2 * j] = f2bf(k0v * C[j] - k1v * Sn[j]);
    ksh[2 * j + 1] = f2bf(k1v * C[j] + k0v * Sn[j]);
  }
  *reinterpret_cast<uint4*>(qo + base) = *reinterpret_cast<uint4*>(qsh);
  *reinterpret_cast<uint4*>(ko + base) = *reinterpret_cast<uint4*>(ksh);
}

// ---------------- attention pass A: rcp[bh][l] = 1 / sum_s exp2(qk) ----------------
// grid 512 = 8 XCD * 4 bh * 16 lblk; 128 L rows/block (32/wave); 32x32x16 MFMA.
__global__ __launch_bounds__(256, 3) void passa_kernel(
    const short* __restrict__ qs, const short* __restrict__ ks,
    float* __restrict__ rcpbuf) {
  __shared__ char smem[49152];  // 3 x 16KB K bufs
  const int bid = blockIdx.x;
  const int xcd = bid & 7, jj = bid >> 3;  // jj 0..63
  const int bh = xcd * 4 + (jj >> 4);
  const int lblk = jj & 15;
  const int b = bh >> 3, h = bh & 7;
  const int l0 = lblk * 128;
  const int tid = threadIdx.x;
  const int wave = tid >> 6, lane = tid & 63;
  const int l31 = lane & 31, lhg = lane >> 5;

  // K staging: tile [64][256B], swizzle ^((row&7)<<4)
  const short* ksrc[4];
  int kq[4];
#pragma unroll
  for (int i = 0; i < 4; i++) {
    int q = i * 4096 + tid * 16;
    kq[i] = q;
    int row = q >> 8, off = (q & 255) ^ ((row & 7) << 4);
    ksrc[i] = ks + (((size_t)b * Sc + row) * Hc + h) * Ec + (off >> 1);
  }

  // Q frags: B-operand of 32x32x16, 8 k-steps; lane holds col=l31, k-slots 8*lhg..+7
  bf16x8 qf[8];
  {
    const char* qp = (const char*)(qs + (((size_t)b * Lc + l0 + wave * 32 + l31) * Hc + h) * Ec);
#pragma unroll
    for (int kt = 0; kt < 8; kt++)
      qf[kt] = *reinterpret_cast<const bf16x8*>(qp + kt * 32 + 16 * lhg);
  }
  __builtin_amdgcn_sched_barrier(0);

#define STAGE_A(buf, s0)                                  \
  {                                                       \
    char* Kb_ = smem + (buf)*16384;                       \
    gload16(ksrc[0] + (size_t)(s0)*1024, Kb_ + kq[0]);    \
    gload16(ksrc[1] + (size_t)(s0)*1024, Kb_ + kq[1]);    \
    gload16(ksrc[2] + (size_t)(s0)*1024, Kb_ + kq[2]);    \
    gload16(ksrc[3] + (size_t)(s0)*1024, Kb_ + kq[3]);    \
  }

  STAGE_A(0, 0);
  STAGE_A(1, 64);
  asm volatile("s_waitcnt vmcnt(4)" ::: "memory");
  __builtin_amdgcn_s_barrier();
  float ra = 0.f, rb = 0.f, rc = 0.f, rd = 0.f;
  int cur = 0;
  for (int t = 0; t < 32; t++) {
    int nb = cur + 2;
    if (nb >= 3) nb -= 3;
    STAGE_A(nb, (t + 2 < 32) ? (t + 2) * 64 : 0);
    __builtin_amdgcn_sched_barrier(0);
    const char* KB_ = smem + cur * 16384;
    f32x16 d0 = {}, d1 = {};
    __builtin_amdgcn_s_setprio(1);
#pragma unroll
    for (int kt = 0; kt < 8; kt++) {
      int row0 = l31, row1 = 32 + l31;
      bf16x8 k0 = *reinterpret_cast<const bf16x8*>(
          KB_ + row0 * 256 + ((kt * 32 + 16 * lhg) ^ ((row0 & 7) << 4)));
      bf16x8 k1 = *reinterpret_cast<const bf16x8*>(
          KB_ + row1 * 256 + ((kt * 32 + 16 * lhg) ^ ((row1 & 7) << 4)));
      d0 = mfma32(k0, qf[kt], d0);
      d1 = mfma32(k1, qf[kt], d1);
    }
    __builtin_amdgcn_s_setprio(0);
#pragma unroll
    for (int r = 0; r < 16; r += 4) {
      ra += exp2f(d0[r]) + exp2f(d1[r]);
      rb += exp2f(d0[r + 1]) + exp2f(d1[r + 1]);
      rc += exp2f(d0[r + 2]) + exp2f(d1[r + 2]);
      rd += exp2f(d0[r + 3]) + exp2f(d1[r + 3]);
    }
    asm volatile("s_waitcnt vmcnt(4) lgkmcnt(0)" ::: "memory");
    __builtin_amdgcn_sched_barrier(0);
    __builtin_amdgcn_s_barrier();
    cur = (cur == 2) ? 0 : cur + 1;
  }
#undef STAGE_A
  float rs = (ra + rb) + (rc + rd);
  rs += __shfl_xor(rs, 32);
  if (lane < 32)
    rcpbuf[(size_t)bh * Lc + l0 + wave * 32 + l31] = 1.0f / rs;
}

// ---------------- attention pass B ----------------
// grid 512 = 8 XCD * 4 bh * 16 lblk; 128 L rows/block (2x16 per wave);
// s-tile 32, 3x(K 8K + V 8K) bufs. Stores issued AFTER PV; vmcnt(8) keeps
// stage(t+2)+stores(t) in flight, drains only stage(t+1) & stores(t-1).
__global__ __launch_bounds__(256, 3) void attn_kernel(
    const short* __restrict__ qs, const short* __restrict__ ks,
    const short* __restrict__ vT, const short* __restrict__ up,
    const float* __restrict__ rcpbuf, float* __restrict__ attn_out,
    short* __restrict__ gate) {
  __shared__ char smem[49152];
  const int bid = blockIdx.x;
  const int xcd = bid & 7, jj = bid >> 3;  // jj 0..63
  const int bh = xcd * 4 + (jj >> 4);
  const int lblk = jj & 15;
  const int b = bh >> 3, h = bh & 7;
  const int l0 = lblk * 128;
  const int tid = threadIdx.x;
  const int wave = tid >> 6, lane = tid & 63;
  const int lquad = lane >> 4, l15 = lane & 15;

  // K staging: rows of 256B, swizzle ^((row&7)<<4)
  const short* ksrc[2];
  int kq[2];
#pragma unroll
  for (int i = 0; i < 2; i++) {
    int q = i * 4096 + tid * 16;
    kq[i] = q;
    int row = q >> 8, off = (q & 255) ^ ((row & 7) << 4);
    ksrc[i] = ks + (((size_t)b * Sc + row) * Hc + h) * Ec + (off >> 1);
  }
  // V staging: tile [128][32] bf16, 64B rows, additive chunk rotation (16B chunks)
  const short* vsrc[2];
  int vq[2];
#pragma unroll
  for (int i = 0; i < 2; i++) {
    int q = i * 4096 + tid * 16;
    vq[i] = q;
    int rv = q >> 6;
    int j = (q >> 4) & 3;
    int c = (j - (rv & 3)) & 3;
    vsrc[i] = vT + ((size_t)bh * UVc + rv) * Sc + (c << 3);
  }

  // Q fragments (B-operand, contiguous-k convention), 2 L-groups per wave
  bf16x8 qf[2][4];
  float rcp[2];
#pragma unroll
  for (int cf = 0; cf < 2; cf++) {
    int lrow = l0 + wave * 32 + cf * 16 + l15;
    const short* qp = qs + (((size_t)b * Lc + lrow) * Hc + h) * Ec;
#pragma unroll
    for (int kt = 0; kt < 4; kt++)
      qf[cf][kt] = *reinterpret_cast<const bf16x8*>(qp + kt * 32 + lquad * 8);
    rcp[cf] = rcpbuf[(size_t)bh * Lc + lrow];
  }
  __builtin_amdgcn_sched_barrier(0);

#define STAGE_B(buf, s0)                                  \
  {                                                       \
    char* Kb_ = smem + (buf)*8192;                        \
    char* Vb_ = smem + 24576 + (buf)*8192;                \
    gload16(ksrc[0] + (size_t)(s0)*1024, Kb_ + kq[0]);    \
    gload16(ksrc[1] + (size_t)(s0)*1024, Kb_ + kq[1]);    \
    gload16(vsrc[0] + (s0), Vb_ + vq[0]);                 \
    gload16(vsrc[1] + (s0), Vb_ + vq[1]);                 \
  }

  STAGE_B(0, 0);
  STAGE_B(1, 32);
  asm volatile("s_waitcnt vmcnt(4)" ::: "memory");
  __builtin_amdgcn_s_barrier();
  f32x4 ctx[8][2] = {};
  int cur = 0;
  for (int t = 0; t < 64; t++) {
    const int s0 = t * 32;
    int nb = cur + 2;
    if (nb >= 3) nb -= 3;
    STAGE_B(nb, (t + 2 < 64) ? s0 + 64 : 0);
    __builtin_amdgcn_sched_barrier(0);
    const char* KB_ = smem + cur * 8192;
    const char* VB_ = smem + 24576 + cur * 8192;
    f32x4 d[2][2] = {};
    __builtin_amdgcn_s_setprio(1);
#pragma unroll
    for (int kt = 0; kt < 4; kt++)
#pragma unroll
      for (int sf = 0; sf < 2; sf++) {
        int row = sf * 16 + l15;
        bf16x8 kf = *reinterpret_cast<const bf16x8*>(
            KB_ + row * 256 + ((kt * 64 + lquad * 16) ^ ((row & 7) << 4)));
        d[sf][0] = mfma16(kf, qf[0][kt], d[sf][0]);
        d[sf][1] = mfma16(kf, qf[1][kt], d[sf][1]);
      }
    __builtin_amdgcn_s_setprio(0);
#pragma unroll
    for (int sf = 0; sf < 2; sf++)
#pragma unroll
      for (int cf = 0; cf < 2; cf++)
#pragma unroll
        for (int r = 0; r < 4; r++)
          d[sf][cf][r] = exp2f(d[sf][cf][r]) * rcp[cf];
    bf16x8 pb[2];
#pragma unroll
    for (int cf = 0; cf < 2; cf++)
#pragma unroll
      for (int r = 0; r < 4; r++) {
        pb[cf][r] = f2bf(d[0][cf][r]);
        pb[cf][4 + r] = f2bf(d[1][cf][r]);
      }
    __builtin_amdgcn_s_setprio(1);
#pragma unroll
    for (int df = 0; df < 8; df++) {
      int dd = df * 16 + l15;
      const char* vrow = VB_ + dd * 64;
      int half = (lquad & 1) * 8;
      int clo = ((lquad >> 1) + (dd & 3)) & 3;
      int chi = ((lquad >> 1) + 2 + (dd & 3)) & 3;
      bf16x4 lo = *reinterpret_cast<const bf16x4*>(vrow + clo * 16 + half);
      bf16x4 hi = *reinterpret_cast<const bf16x4*>(vrow + chi * 16 + half);
      bf16x8 vf = __builtin_shufflevector(lo, hi, 0, 1, 2, 3, 4, 5, 6, 7);
      ctx[df][0] = mfma16(vf, pb[0], ctx[df][0]);
      ctx[df][1] = mfma16(vf, pb[1], ctx[df][1]);
    }
    __builtin_amdgcn_s_setprio(0);
    // attn writes AFTER PV: they ride in the vmem queue through the barrier
#pragma unroll
    for (int cf = 0; cf < 2; cf++) {
      int lrow = l0 + wave * 32 + cf * 16 + l15;
      float* arow = attn_out + ((size_t)bh * Lc + lrow) * Sc + s0 + lquad * 4;
      __builtin_nontemporal_store(d[0][cf], reinterpret_cast<f32x4*>(arow));
      __builtin_nontemporal_store(d[1][cf], reinterpret_cast<f32x4*>(arow + 16));
    }
    // keep newest 8 (stage t+2 loads + this iter's stores) in flight;
    // drains stage(t+1) [needed next iter] and stores(t-1) [a full iter old]
    asm volatile("s_waitcnt vmcnt(8) lgkmcnt(0)" ::: "memory");
    __builtin_amdgcn_sched_barrier(0);
    __builtin_amdgcn_s_barrier();
    cur = (cur == 2) ? 0 : cur + 1;
  }
#undef STAGE_B

  // ---- epilogue: gate = u_p * ctx, direct from regs ----
#pragma unroll
  for (int cf = 0; cf < 2; cf++) {
    int lrow = l0 + wave * 32 + cf * 16 + l15;
    size_t base = ((size_t)b * Lc + lrow) * HEc + h * UVc;
    const short* ub = up + base;
    short* gp = gate + base;
#pragma unroll
    for (int df = 0; df < 8; df++) {
      int doff = df * 16 + lquad * 4;
      bf16x4 uv = *reinterpret_cast<const bf16x4*>(ub + doff);
      bf16x4 gv;
#pragma unroll
      for (int r = 0; r < 4; r++)
        gv[r] = f2bf(bf2f(uv[r]) * ctx[df][cf][r]);
      *reinterpret_cast<bf16x4*>(gp + doff) = gv;
    }
  }
}

// ---------------- launch ----------------
extern "C" void kernel_launch(void* const* d_in, const int* in_sizes, int n_in,
                              void* d_out, int out_size, void* d_ws, size_t ws_size,
                              hipStream_t stream) {
  const float* u_in = (const float*)d_in[0];
  const float* qry = (const float*)d_in[1];
  // d_in[2] = keys : unused (use_aff shared qk projection)
  const float* vals = (const float*)d_in[3];
  const float* Wqk = (const float*)d_in[4];
  const float* bqk = (const float*)d_in[5];
  const float* Wv = (const float*)d_in[6];
  const float* bv = (const float*)d_in[7];
  const float* Wu = (const float*)d_in[8];
  const float* bu = (const float*)d_in[9];
  const float* Wo = (const float*)d_in[10];
  const float* bo = (const float*)d_in[11];
  const float* qg = (const float*)d_in[12];
  const float* qb = (const float*)d_in[13];
  const float* kg = (const float*)d_in[14];
  const float* kb = (const float*)d_in[15];

  char* w = (char*)d_ws;
  short* WT0 = (short*)w; w += (size_t)1024 * 1024 * 2;
  short* WT1 = (short*)w; w += (size_t)1024 * 1024 * 2;
  short* WT2 = (short*)w; w += (size_t)1024 * 1024 * 2;
  short* WT3 = (short*)w; w += (size_t)1024 * 1024 * 2;
  float2* cstab = (float2*)w; w += (size_t)2048 * 512 * 8;
  float* rcpb = (float*)w; w += (size_t)32 * 2048 * 4;
  const size_t BUF = (size_t)BLc * HEc * 2;  // 16.78 MB
  short* C1 = (short*)w; w += BUF;   // bf16 queries; reused as gate after gemm1
  short* C2 = (short*)w; w += BUF;   // bf16 values
  short* C3 = (short*)w; w += BUF;   // bf16 u
  short* qkg = (short*)w; w += BUF;  // qk gelu out; kbf aliases it (in-place rope)
  short* qbf = (short*)w; w += BUF;
  short* vTb = (short*)w; w += BUF;
  short* upb = (short*)w; w += BUF;
  short* kbf = qkg;  // in-place: rope_apply reads/writes identical indices
  short* gtb = C1;   // C1 dead after gemm1

  float* o_out = (float*)d_out;
  float* attn_out = o_out + (size_t)BLc * Dc;

  dim3 tb(32, 8);
  cvt3_kernel<<<dim3(4096, 3), 256, 0, stream>>>(qry, vals, u_in, C1, C2, C3);
  wt_trans_kernel<<<dim3(32, 32, 4), tb, 0, stream>>>(Wqk, Wv, Wu, Wo, WT0, WT1, WT2, WT3);
  rope_cs_kernel<<<4096, 256, 0, stream>>>(cstab);

  gemm_kernel<1><<<dim3(64, 8), 256, 0, stream>>>(C1, WT0, bqk, qkg, BLc, HEc, Dc);
  rope_apply_kernel<<<4096, 256, 0, stream>>>(qkg, cstab, qg, qb, kg, kb, qbf, kbf);
  passa_kernel<<<512, 256, 0, stream>>>(qbf, kbf, rcpb);
  gemm_kernel<3><<<dim3(64, 8), 256, 0, stream>>>(C2, WT1, bv, vTb, BLc, HEc, Dc);
  gemm_kernel<1><<<dim3(64, 8), 256, 0, stream>>>(C3, WT2, bu, upb, BLc, HEc, Dc);
  attn_kernel<<<512, 256, 0, stream>>>(qbf, kbf, vTb, upb, rcpb, attn_out, gtb);
  gemm_kernel<0><<<dim3(64, 8), 256, 0, stream>>>(gtb, WT3, bo, o_out, BLc, Dc, HEc);
}

// Round 8
// 387.194 us; speedup vs baseline: 1.0620x; 1.0620x over previous
//
#include <hip/hip_runtime.h>
#include <hip/hip_bf16.h>
#include <math.h>

#define DEVI static __device__ __forceinline__

typedef __attribute__((ext_vector_type(4))) float f32x4;
typedef __attribute__((ext_vector_type(16))) float f32x16;
typedef __attribute__((ext_vector_type(8))) short bf16x8;
typedef __attribute__((ext_vector_type(4))) short bf16x4;

constexpr int Bc = 4, Lc = 2048, Sc = 2048, Dc = 1024, Hc = 8, Ec = 128, UVc = 128;
constexpr int HEc = Hc * Ec;   // 1024
constexpr int BLc = Bc * Lc;   // 8192

// scale * log2(e): folded into q so exp(scale*qk) == exp2(d)
#define QSC (1.44269504088896340f / 11.31370849898476039f)

DEVI unsigned f2bf_bits(float f) {
  unsigned u = __builtin_bit_cast(unsigned, f);
  return (u + 0x7FFFu + ((u >> 16) & 1u)) >> 16;
}
DEVI short f2bf(float f) { return (short)f2bf_bits(f); }
DEVI float bf2f(short s) {
  return __builtin_bit_cast(float, (unsigned)((unsigned short)s) << 16);
}
// gelu via A&S 7.1.26 erf approx (max abs err 1.5e-7): 1 rcp + 1 exp2 + ~7 FMA,
// vs library erff's ~25-30 inst. Error floor far below bf16 quantization.
DEVI float gelu_f(float x) {
  float z = fabsf(x) * 0.7071067811865476f;
  float t = __builtin_amdgcn_rcpf(1.0f + 0.3275911f * z);
  float p = t * (0.254829592f +
            t * (-0.284496736f +
            t * (1.421413741f +
            t * (-1.453152027f + t * 1.061405429f))));
  float e = exp2f(-z * z * 1.4426950408889634f);
  float er = copysignf(1.0f - p * e, x);
  return 0.5f * x * (1.0f + er);
}

DEVI void gload16(const void* gsrc, void* ldst) {
  __builtin_amdgcn_global_load_lds(
      (const __attribute__((address_space(1))) unsigned*)gsrc,
      (__attribute__((address_space(3))) unsigned*)(ldst), 16, 0, 0);
}

DEVI f32x4 mfma16(bf16x8 a, bf16x8 b, f32x4 c) {
  return __builtin_amdgcn_mfma_f32_16x16x32_bf16(a, b, c, 0, 0, 0);
}
DEVI f32x16 mfma32(bf16x8 a, bf16x8 b, f32x16 c) {
  return __builtin_amdgcn_mfma_f32_32x32x16_bf16(a, b, c, 0, 0, 0);
}

// ---------------- prep: f32 -> bf16 convert, 3 tensors in one launch ----------------
__global__ void cvt3_kernel(const float* __restrict__ i0, const float* __restrict__ i1,
                            const float* __restrict__ i2, short* __restrict__ o0,
                            short* __restrict__ o1, short* __restrict__ o2) {
  const float* ins[3] = {i0, i1, i2};
  short* outs[3] = {o0, o1, o2};
  const float* in = ins[blockIdx.y];
  short* out = outs[blockIdx.y];
  size_t i = ((size_t)blockIdx.x * 256 + threadIdx.x) * 8;
  float4 f1 = *reinterpret_cast<const float4*>(in + i);
  float4 f2 = *reinterpret_cast<const float4*>(in + i + 4);
  uint4 pk;
  pk.x = f2bf_bits(f1.x) | (f2bf_bits(f1.y) << 16);
  pk.y = f2bf_bits(f1.z) | (f2bf_bits(f1.w) << 16);
  pk.z = f2bf_bits(f2.x) | (f2bf_bits(f2.y) << 16);
  pk.w = f2bf_bits(f2.z) | (f2bf_bits(f2.w) << 16);
  *reinterpret_cast<uint4*>(out + i) = pk;
}

// ---------------- prep: 4 weight transposes (z<4) + rope cos/sin table (z==4) ----------
__global__ void prep_kernel(const float* __restrict__ W0, const float* __restrict__ W1,
                            const float* __restrict__ W2, const float* __restrict__ W3,
                            short* __restrict__ T0, short* __restrict__ T1,
                            short* __restrict__ T2, short* __restrict__ T3,
                            float2* __restrict__ cs) {
  int tx = threadIdx.x, ty = threadIdx.y;
  if (blockIdx.z == 4) {
    // rope table: 2048x512 entries of (cos,sin); 1024 blocks x 256 thr x 4 elems
    int base = (blockIdx.y * 32 + blockIdx.x) * 256 + ty * 32 + tx;
#pragma unroll
    for (int j = 0; j < 4; j++) {
      int idx = base + j * 262144;
      int t = idx >> 9, i = idx & 511;
      float inv = expf((float)i * (-9.210340371976184f / 512.0f));
      float sv, cv;
      sincosf((float)t * inv, &sv, &cv);
      cs[idx] = make_float2(cv, sv);
    }
    return;
  }
  __shared__ float tbuf[32][33];
  const float* Ws[4] = {W0, W1, W2, W3};
  short* Ts[4] = {T0, T1, T2, T3};
  const float* W = Ws[blockIdx.z];
  short* WT = Ts[blockIdx.z];
  int n0 = blockIdx.x * 32, k0 = blockIdx.y * 32;
#pragma unroll
  for (int i = 0; i < 4; i++) {
    int r = ty + i * 8;
    tbuf[r][tx] = W[(size_t)(k0 + r) * 1024 + n0 + tx];
  }
  __syncthreads();
#pragma unroll
  for (int i = 0; i < 4; i++) {
    int r = ty + i * 8;
    WT[(size_t)(n0 + r) * 1024 + k0 + tx] = f2bf(tbuf[tx][r]);
  }
}

// ---------------- GEMM: C = epi(A @ W + bias); A bf16 [M][K], W as WT[N][K] bf16 ----------
// 128x128 tile, BK=32, 3-buffer LDS pipeline (counted vmcnt, 1 barrier/step).
// EPI: 0 = f32+bias, 1 = gelu->bf16, 3 = gelu->bf16 written transposed to vT layout.
template <int EPI>
__global__ __launch_bounds__(256, 3) void gemm_kernel(
    const short* __restrict__ A, const short* __restrict__ BT,
    const float* __restrict__ bias, void* __restrict__ Cptr, int M, int N, int K) {
  __shared__ char smem[49152];  // A bufs 3x8K @0, B bufs 3x8K @24K
  const int tid = threadIdx.x;
  const int wave = tid >> 6, lane = tid & 63;
  const int lquad = lane >> 4, l15 = lane & 15;
  const int m0 = blockIdx.x * 128, n0 = blockIdx.y * 128;
  const int wr = wave >> 1, wc = wave & 1;
  f32x4 acc[4][4] = {};

  const int q0 = tid * 16, q1 = tid * 16 + 4096;
  const int r0 = q0 >> 6, o0 = (q0 & 63) ^ ((r0 & 3) << 4);
  const int r1 = q1 >> 6, o1 = (q1 & 63) ^ ((r1 & 3) << 4);
  const short* a0 = A + (size_t)(m0 + r0) * K + (o0 >> 1);
  const short* a1 = A + (size_t)(m0 + r1) * K + (o1 >> 1);
  const short* b0 = BT + (size_t)(n0 + r0) * K + (o0 >> 1);
  const short* b1 = BT + (size_t)(n0 + r1) * K + (o1 >> 1);

#define G_STAGE(buf, kt)                     \
  {                                          \
    char* As_ = smem + (buf)*8192;           \
    char* Bs_ = smem + 24576 + (buf)*8192;   \
    gload16(a0 + (kt), As_ + q0);            \
    gload16(a1 + (kt), As_ + q1);            \
    gload16(b0 + (kt), Bs_ + q0);            \
    gload16(b1 + (kt), Bs_ + q1);            \
  }

  G_STAGE(0, 0);
  G_STAGE(1, 32);
  asm volatile("s_waitcnt vmcnt(4)" ::: "memory");
  __builtin_amdgcn_s_barrier();

  const int NT = K >> 5;
  int cur = 0;
  for (int t = 0; t < NT; t++) {
    int nb = cur + 2;
    if (nb >= 3) nb -= 3;
    G_STAGE(nb, (t + 2 < NT) ? (t + 2) * 32 : 0);  // dummy tail keeps vmcnt math uniform
    __builtin_amdgcn_sched_barrier(0);
    const char* As_ = smem + cur * 8192;
    const char* Bs_ = smem + 24576 + cur * 8192;
    const int ko = lquad * 16;
    bf16x8 a[4], b[4];
#pragma unroll
    for (int f = 0; f < 4; f++) {
      int ra = wr * 64 + f * 16 + l15;
      a[f] = *reinterpret_cast<const bf16x8*>(As_ + ra * 64 + (ko ^ ((ra & 3) << 4)));
      int rb = wc * 64 + f * 16 + l15;
      b[f] = *reinterpret_cast<const bf16x8*>(Bs_ + rb * 64 + (ko ^ ((rb & 3) << 4)));
    }
#pragma unroll
    for (int mf = 0; mf < 4; mf++)
#pragma unroll
      for (int nf = 0; nf < 4; nf++)
        acc[mf][nf] = mfma16(a[mf], b[nf], acc[mf][nf]);
    asm volatile("s_waitcnt vmcnt(4) lgkmcnt(0)" ::: "memory");
    __builtin_amdgcn_sched_barrier(0);
    __builtin_amdgcn_s_barrier();
    cur = (cur == 2) ? 0 : cur + 1;
  }
#undef G_STAGE

#pragma unroll
  for (int mf = 0; mf < 4; mf++) {
#pragma unroll
    for (int nf = 0; nf < 4; nf++) {
      const int mrow = m0 + wr * 64 + mf * 16 + 4 * lquad;
      const int ncol = n0 + wc * 64 + nf * 16 + l15;
      const float bval = bias[ncol];
      if constexpr (EPI == 3) {
        // transposed V write: vT[((b*8+h)*128+d)*2048 + s], s = 4 consecutive (over r)
        int hh = ncol >> 7, dd = ncol & 127;
        int bb = mrow >> 11, ss = mrow & 2047;
        bf16x4 gv;
#pragma unroll
        for (int r = 0; r < 4; r++) gv[r] = f2bf(gelu_f(acc[mf][nf][r] + bval));
        *reinterpret_cast<bf16x4*>((short*)Cptr + (((size_t)bb * 8 + hh) * 128 + dd) * 2048 + ss) = gv;
      } else if constexpr (EPI == 1) {
#pragma unroll
        for (int r = 0; r < 4; r++)
          ((short*)Cptr)[(size_t)(mrow + r) * N + ncol] = f2bf(gelu_f(acc[mf][nf][r] + bval));
      } else {
#pragma unroll
        for (int r = 0; r < 4; r++)
          ((float*)Cptr)[(size_t)(mrow + r) * N + ncol] = acc[mf][nf][r] + bval;
      }
    }
  }
}

// ---------------- rope apply: qk_gelu -> q (pre-scaled by QSC), k ----------------
__global__ void rope_apply_kernel(const short* __restrict__ qkg,
                                  const float2* __restrict__ cstab,
                                  const float* __restrict__ qg, const float* __restrict__ qb,
                                  const float* __restrict__ kg, const float* __restrict__ kb,
                                  short* __restrict__ qo, short* __restrict__ ko) {
  int tid = blockIdx.x * 256 + threadIdx.x;
  size_t base = (size_t)tid * 8;
  int bl = (int)(base >> 10);
  int rem = (int)(base & 1023);
  int e0 = rem & 127;
  int t = bl & 2047;
  int pf = rem >> 1;  // flat pair index
  uint4 raw = *reinterpret_cast<const uint4*>(qkg + base);
  short sh[8];
  *reinterpret_cast<uint4*>(sh) = raw;
  const float* csf = (const float*)cstab + (size_t)t * 1024 + 2 * pf;
  float4 p01 = *reinterpret_cast<const float4*>(csf);
  float4 p23 = *reinterpret_cast<const float4*>(csf + 4);
  float C[4] = {p01.x, p01.z, p23.x, p23.z};
  float Sn[4] = {p01.y, p01.w, p23.y, p23.w};
  float4 qga = *reinterpret_cast<const float4*>(qg + e0);
  float4 qgb = *reinterpret_cast<const float4*>(qg + e0 + 4);
  float4 qba = *reinterpret_cast<const float4*>(qb + e0);
  float4 qbb = *reinterpret_cast<const float4*>(qb + e0 + 4);
  float4 kga = *reinterpret_cast<const float4*>(kg + e0);
  float4 kgb = *reinterpret_cast<const float4*>(kg + e0 + 4);
  float4 kba = *reinterpret_cast<const float4*>(kb + e0);
  float4 kbb = *reinterpret_cast<const float4*>(kb + e0 + 4);
  float QG[8] = {qga.x, qga.y, qga.z, qga.w, qgb.x, qgb.y, qgb.z, qgb.w};
  float QB[8] = {qba.x, qba.y, qba.z, qba.w, qbb.x, qbb.y, qbb.z, qbb.w};
  float KG[8] = {kga.x, kga.y, kga.z, kga.w, kgb.x, kgb.y, kgb.z, kgb.w};
  float KB[8] = {kba.x, kba.y, kba.z, kba.w, kbb.x, kbb.y, kbb.z, kbb.w};
  short qsh[8], ksh[8];
#pragma unroll
  for (int j = 0; j < 4; j++) {
    float x0 = bf2f(sh[2 * j]), x1 = bf2f(sh[2 * j + 1]);
    float q0 = x0 * QG[2 * j] + QB[2 * j];
    float q1 = x1 * QG[2 * j + 1] + QB[2 * j + 1];
    qsh[2 * j] = f2bf((q0 * C[j] - q1 * Sn[j]) * QSC);
    qsh[2 * j + 1] = f2bf((q1 * C[j] + q0 * Sn[j]) * QSC);
    float k0v = x0 * KG[2 * j] + KB[2 * j];
    float k1v = x1 * KG[2 * j + 1] + KB[2 * j + 1];
    ksh[2 * j] = f2bf(k0v * C[j] - k1v * Sn[j]);
    ksh[2 * j + 1] = f2bf(k1v * C[j] + k0v * Sn[j]);
  }
  *reinterpret_cast<uint4*>(qo + base) = *reinterpret_cast<uint4*>(qsh);
  *reinterpret_cast<uint4*>(ko + base) = *reinterpret_cast<uint4*>(ksh);
}

// ---------------- attention pass A: rcp[bh][l] = 1 / sum_s exp2(qk) ----------------
// grid 512 = 8 XCD * 4 bh * 16 lblk; 128 L rows/block (32/wave); 32x32x16 MFMA.
__global__ __launch_bounds__(256, 3) void passa_kernel(
    const short* __restrict__ qs, const short* __restrict__ ks,
    float* __restrict__ rcpbuf) {
  __shared__ char smem[49152];  // 3 x 16KB K bufs
  const int bid = blockIdx.x;
  const int xcd = bid & 7, jj = bid >> 3;  // jj 0..63
  const int bh = xcd * 4 + (jj >> 4);
  const int lblk = jj & 15;
  const int b = bh >> 3, h = bh & 7;
  const int l0 = lblk * 128;
  const int tid = threadIdx.x;
  const int wave = tid >> 6, lane = tid & 63;
  const int l31 = lane & 31, lhg = lane >> 5;

  // K staging: tile [64][256B], swizzle ^((row&7)<<4)
  const short* ksrc[4];
  int kq[4];
#pragma unroll
  for (int i = 0; i < 4; i++) {
    int q = i * 4096 + tid * 16;
    kq[i] = q;
    int row = q >> 8, off = (q & 255) ^ ((row & 7) << 4);
    ksrc[i] = ks + (((size_t)b * Sc + row) * Hc + h) * Ec + (off >> 1);
  }

  // Q frags: B-operand of 32x32x16, 8 k-steps; lane holds col=l31, k-slots 8*lhg..+7
  bf16x8 qf[8];
  {
    const char* qp = (const char*)(qs + (((size_t)b * Lc + l0 + wave * 32 + l31) * Hc + h) * Ec);
#pragma unroll
    for (int kt = 0; kt < 8; kt++)
      qf[kt] = *reinterpret_cast<const bf16x8*>(qp + kt * 32 + 16 * lhg);
  }
  __builtin_amdgcn_sched_barrier(0);

#define STAGE_A(buf, s0)                                  \
  {                                                       \
    char* Kb_ = smem + (buf)*16384;                       \
    gload16(ksrc[0] + (size_t)(s0)*1024, Kb_ + kq[0]);    \
    gload16(ksrc[1] + (size_t)(s0)*1024, Kb_ + kq[1]);    \
    gload16(ksrc[2] + (size_t)(s0)*1024, Kb_ + kq[2]);    \
    gload16(ksrc[3] + (size_t)(s0)*1024, Kb_ + kq[3]);    \
  }

  STAGE_A(0, 0);
  STAGE_A(1, 64);
  asm volatile("s_waitcnt vmcnt(4)" ::: "memory");
  __builtin_amdgcn_s_barrier();
  float ra = 0.f, rb = 0.f, rc = 0.f, rd = 0.f;
  int cur = 0;
  for (int t = 0; t < 32; t++) {
    int nb = cur + 2;
    if (nb >= 3) nb -= 3;
    STAGE_A(nb, (t + 2 < 32) ? (t + 2) * 64 : 0);
    __builtin_amdgcn_sched_barrier(0);
    const char* KB_ = smem + cur * 16384;
    f32x16 d0 = {}, d1 = {};
    __builtin_amdgcn_s_setprio(1);
#pragma unroll
    for (int kt = 0; kt < 8; kt++) {
      int row0 = l31, row1 = 32 + l31;
      bf16x8 k0 = *reinterpret_cast<const bf16x8*>(
          KB_ + row0 * 256 + ((kt * 32 + 16 * lhg) ^ ((row0 & 7) << 4)));
      bf16x8 k1 = *reinterpret_cast<const bf16x8*>(
          KB_ + row1 * 256 + ((kt * 32 + 16 * lhg) ^ ((row1 & 7) << 4)));
      d0 = mfma32(k0, qf[kt], d0);
      d1 = mfma32(k1, qf[kt], d1);
    }
    __builtin_amdgcn_s_setprio(0);
#pragma unroll
    for (int r = 0; r < 16; r += 4) {
      ra += exp2f(d0[r]) + exp2f(d1[r]);
      rb += exp2f(d0[r + 1]) + exp2f(d1[r + 1]);
      rc += exp2f(d0[r + 2]) + exp2f(d1[r + 2]);
      rd += exp2f(d0[r + 3]) + exp2f(d1[r + 3]);
    }
    asm volatile("s_waitcnt vmcnt(4) lgkmcnt(0)" ::: "memory");
    __builtin_amdgcn_sched_barrier(0);
    __builtin_amdgcn_s_barrier();
    cur = (cur == 2) ? 0 : cur + 1;
  }
#undef STAGE_A
  float rs = (ra + rb) + (rc + rd);
  rs += __shfl_xor(rs, 32);
  if (lane < 32)
    rcpbuf[(size_t)bh * Lc + l0 + wave * 32 + l31] = 1.0f / rs;
}

// ---------------- attention pass B ----------------
// grid 512 = 8 XCD * 4 bh * 16 lblk; 128 L rows/block (2x16 per wave); s-tile 32.
// Schedule: [QK | exp | stores | cvt | PV | STAGE(t+2) | vmcnt(8) | barrier]:
// the wait drains exactly stage(t+1) (1 iter old) + stores(t-1); keeps
// stores(t) and stage(t+2) in flight across the barrier.
__global__ __launch_bounds__(256, 3) void attn_kernel(
    const short* __restrict__ qs, const short* __restrict__ ks,
    const short* __restrict__ vT, const short* __restrict__ up,
    const float* __restrict__ rcpbuf, float* __restrict__ attn_out,
    short* __restrict__ gate) {
  __shared__ char smem[49152];
  const int bid = blockIdx.x;
  const int xcd = bid & 7, jj = bid >> 3;  // jj 0..63
  const int bh = xcd * 4 + (jj >> 4);
  const int lblk = jj & 15;
  const int b = bh >> 3, h = bh & 7;
  const int l0 = lblk * 128;
  const int tid = threadIdx.x;
  const int wave = tid >> 6, lane = tid & 63;
  const int lquad = lane >> 4, l15 = lane & 15;

  // K staging: rows of 256B, swizzle ^((row&7)<<4)
  const short* ksrc[2];
  int kq[2];
#pragma unroll
  for (int i = 0; i < 2; i++) {
    int q = i * 4096 + tid * 16;
    kq[i] = q;
    int row = q >> 8, off = (q & 255) ^ ((row & 7) << 4);
    ksrc[i] = ks + (((size_t)b * Sc + row) * Hc + h) * Ec + (off >> 1);
  }
  // V staging: tile [128][32] bf16, 64B rows, additive chunk rotation (16B chunks)
  const short* vsrc[2];
  int vq[2];
#pragma unroll
  for (int i = 0; i < 2; i++) {
    int q = i * 4096 + tid * 16;
    vq[i] = q;
    int rv = q >> 6;
    int j = (q >> 4) & 3;
    int c = (j - (rv & 3)) & 3;
    vsrc[i] = vT + ((size_t)bh * UVc + rv) * Sc + (c << 3);
  }

  // Q fragments (B-operand, contiguous-k convention), 2 L-groups per wave
  bf16x8 qf[2][4];
  float rcp[2];
#pragma unroll
  for (int cf = 0; cf < 2; cf++) {
    int lrow = l0 + wave * 32 + cf * 16 + l15;
    const short* qp = qs + (((size_t)b * Lc + lrow) * Hc + h) * Ec;
#pragma unroll
    for (int kt = 0; kt < 4; kt++)
      qf[cf][kt] = *reinterpret_cast<const bf16x8*>(qp + kt * 32 + lquad * 8);
    rcp[cf] = rcpbuf[(size_t)bh * Lc + lrow];
  }
  __builtin_amdgcn_sched_barrier(0);

#define STAGE_B(buf, s0)                                  \
  {                                                       \
    char* Kb_ = smem + (buf)*8192;                        \
    char* Vb_ = smem + 24576 + (buf)*8192;                \
    gload16(ksrc[0] + (size_t)(s0)*1024, Kb_ + kq[0]);    \
    gload16(ksrc[1] + (size_t)(s0)*1024, Kb_ + kq[1]);    \
    gload16(vsrc[0] + (s0), Vb_ + vq[0]);                 \
    gload16(vsrc[1] + (s0), Vb_ + vq[1]);                 \
  }

  STAGE_B(0, 0);
  STAGE_B(1, 32);
  asm volatile("s_waitcnt vmcnt(4)" ::: "memory");
  __builtin_amdgcn_s_barrier();
  f32x4 ctx[8][2] = {};
  int cur = 0;
  for (int t = 0; t < 64; t++) {
    const int s0 = t * 32;
    const char* KB_ = smem + cur * 8192;
    const char* VB_ = smem + 24576 + cur * 8192;
    f32x4 d[2][2] = {};
    __builtin_amdgcn_s_setprio(1);
#pragma unroll
    for (int kt = 0; kt < 4; kt++)
#pragma unroll
      for (int sf = 0; sf < 2; sf++) {
        int row = sf * 16 + l15;
        bf16x8 kf = *reinterpret_cast<const bf16x8*>(
            KB_ + row * 256 + ((kt * 64 + lquad * 16) ^ ((row & 7) << 4)));
        d[sf][0] = mfma16(kf, qf[0][kt], d[sf][0]);
        d[sf][1] = mfma16(kf, qf[1][kt], d[sf][1]);
      }
    __builtin_amdgcn_s_setprio(0);
#pragma unroll
    for (int sf = 0; sf < 2; sf++)
#pragma unroll
      for (int cf = 0; cf < 2; cf++)
#pragma unroll
        for (int r = 0; r < 4; r++)
          d[sf][cf][r] = exp2f(d[sf][cf][r]) * rcp[cf];
    // stores issued early: a full iteration to retire before their drain
#pragma unroll
    for (int cf = 0; cf < 2; cf++) {
      int lrow = l0 + wave * 32 + cf * 16 + l15;
      float* arow = attn_out + ((size_t)bh * Lc + lrow) * Sc + s0 + lquad * 4;
      __builtin_nontemporal_store(d[0][cf], reinterpret_cast<f32x4*>(arow));
      __builtin_nontemporal_store(d[1][cf], reinterpret_cast<f32x4*>(arow + 16));
    }
    bf16x8 pb[2];
#pragma unroll
    for (int cf = 0; cf < 2; cf++)
#pragma unroll
      for (int r = 0; r < 4; r++) {
        pb[cf][r] = f2bf(d[0][cf][r]);
        pb[cf][4 + r] = f2bf(d[1][cf][r]);
      }
    __builtin_amdgcn_s_setprio(1);
#pragma unroll
    for (int df = 0; df < 8; df++) {
      int dd = df * 16 + l15;
      const char* vrow = VB_ + dd * 64;
      int half = (lquad & 1) * 8;
      int clo = ((lquad >> 1) + (dd & 3)) & 3;
      int chi = ((lquad >> 1) + 2 + (dd & 3)) & 3;
      bf16x4 lo = *reinterpret_cast<const bf16x4*>(vrow + clo * 16 + half);
      bf16x4 hi = *reinterpret_cast<const bf16x4*>(vrow + chi * 16 + half);
      bf16x8 vf = __builtin_shufflevector(lo, hi, 0, 1, 2, 3, 4, 5, 6, 7);
      ctx[df][0] = mfma16(vf, pb[0], ctx[df][0]);
      ctx[df][1] = mfma16(vf, pb[1], ctx[df][1]);
    }
    __builtin_amdgcn_s_setprio(0);
    // stage for t+2 issued last; vmcnt(8) keeps it + this iter's stores in flight
    {
      int nb = cur + 2;
      if (nb >= 3) nb -= 3;
      STAGE_B(nb, (t + 2 < 64) ? s0 + 64 : 0);
    }
    asm volatile("s_waitcnt vmcnt(8) lgkmcnt(0)" ::: "memory");
    __builtin_amdgcn_sched_barrier(0);
    __builtin_amdgcn_s_barrier();
    cur = (cur == 2) ? 0 : cur + 1;
  }
#undef STAGE_B

  // ---- epilogue: gate = u_p * ctx, direct from regs ----
#pragma unroll
  for (int cf = 0; cf < 2; cf++) {
    int lrow = l0 + wave * 32 + cf * 16 + l15;
    size_t base = ((size_t)b * Lc + lrow) * HEc + h * UVc;
    const short* ub = up + base;
    short* gp = gate + base;
#pragma unroll
    for (int df = 0; df < 8; df++) {
      int doff = df * 16 + lquad * 4;
      bf16x4 uv = *reinterpret_cast<const bf16x4*>(ub + doff);
      bf16x4 gv;
#pragma unroll
      for (int r = 0; r < 4; r++)
        gv[r] = f2bf(bf2f(uv[r]) * ctx[df][cf][r]);
      *reinterpret_cast<bf16x4*>(gp + doff) = gv;
    }
  }
}

// ---------------- launch ----------------
extern "C" void kernel_launch(void* const* d_in, const int* in_sizes, int n_in,
                              void* d_out, int out_size, void* d_ws, size_t ws_size,
                              hipStream_t stream) {
  const float* u_in = (const float*)d_in[0];
  const float* qry = (const float*)d_in[1];
  // d_in[2] = keys : unused (use_aff shared qk projection)
  const float* vals = (const float*)d_in[3];
  const float* Wqk = (const float*)d_in[4];
  const float* bqk = (const float*)d_in[5];
  const float* Wv = (const float*)d_in[6];
  const float* bv = (const float*)d_in[7];
  const float* Wu = (const float*)d_in[8];
  const float* bu = (const float*)d_in[9];
  const float* Wo = (const float*)d_in[10];
  const float* bo = (const float*)d_in[11];
  const float* qg = (const float*)d_in[12];
  const float* qb = (const float*)d_in[13];
  const float* kg = (const float*)d_in[14];
  const float* kb = (const float*)d_in[15];

  char* w = (char*)d_ws;
  short* WT0 = (short*)w; w += (size_t)1024 * 1024 * 2;
  short* WT1 = (short*)w; w += (size_t)1024 * 1024 * 2;
  short* WT2 = (short*)w; w += (size_t)1024 * 1024 * 2;
  short* WT3 = (short*)w; w += (size_t)1024 * 1024 * 2;
  float2* cstab = (float2*)w; w += (size_t)2048 * 512 * 8;
  float* rcpb = (float*)w; w += (size_t)32 * 2048 * 4;
  const size_t BUF = (size_t)BLc * HEc * 2;  // 16.78 MB
  short* C1 = (short*)w; w += BUF;   // bf16 queries; reused as gate after gemm1
  short* C2 = (short*)w; w += BUF;   // bf16 values
  short* C3 = (short*)w; w += BUF;   // bf16 u
  short* qkg = (short*)w; w += BUF;  // qk gelu out; kbf aliases it (in-place rope)
  short* qbf = (short*)w; w += BUF;
  short* vTb = (short*)w; w += BUF;
  short* upb = (short*)w; w += BUF;
  short* kbf = qkg;  // in-place: rope_apply reads/writes identical indices
  short* gtb = C1;   // C1 dead after gemm1

  float* o_out = (float*)d_out;
  float* attn_out = o_out + (size_t)BLc * Dc;

  dim3 tb(32, 8);
  cvt3_kernel<<<dim3(4096, 3), 256, 0, stream>>>(qry, vals, u_in, C1, C2, C3);
  prep_kernel<<<dim3(32, 32, 5), tb, 0, stream>>>(Wqk, Wv, Wu, Wo, WT0, WT1, WT2, WT3, cstab);

  gemm_kernel<1><<<dim3(64, 8), 256, 0, stream>>>(C1, WT0, bqk, qkg, BLc, HEc, Dc);
  rope_apply_kernel<<<4096, 256, 0, stream>>>(qkg, cstab, qg, qb, kg, kb, qbf, kbf);
  passa_kernel<<<512, 256, 0, stream>>>(qbf, kbf, rcpb);
  gemm_kernel<3><<<dim3(64, 8), 256, 0, stream>>>(C2, WT1, bv, vTb, BLc, HEc, Dc);
  gemm_kernel<1><<<dim3(64, 8), 256, 0, stream>>>(C3, WT2, bu, upb, BLc, HEc, Dc);
  attn_kernel<<<512, 256, 0, stream>>>(qbf, kbf, vTb, upb, rcpb, attn_out, gtb);
  gemm_kernel<0><<<dim3(64, 8), 256, 0, stream>>>(gtb, WT3, bo, o_out, BLc, Dc, HEc);
}

// Round 9
// 378.787 us; speedup vs baseline: 1.0855x; 1.0222x over previous
//
#include <hip/hip_runtime.h>
#include <hip/hip_bf16.h>
#include <math.h>

#define DEVI static __device__ __forceinline__

typedef __attribute__((ext_vector_type(4))) float f32x4;
typedef __attribute__((ext_vector_type(16))) float f32x16;
typedef __attribute__((ext_vector_type(8))) short bf16x8;
typedef __attribute__((ext_vector_type(4))) short bf16x4;

constexpr int Bc = 4, Lc = 2048, Sc = 2048, Dc = 1024, Hc = 8, Ec = 128, UVc = 128;
constexpr int HEc = Hc * Ec;   // 1024
constexpr int BLc = Bc * Lc;   // 8192

// scale * log2(e): folded into q so exp(scale*qk) == exp2(d)
#define QSC (1.44269504088896340f / 11.31370849898476039f)

DEVI unsigned f2bf_bits(float f) {
  unsigned u = __builtin_bit_cast(unsigned, f);
  return (u + 0x7FFFu + ((u >> 16) & 1u)) >> 16;
}
DEVI short f2bf(float f) { return (short)f2bf_bits(f); }
DEVI float bf2f(short s) {
  return __builtin_bit_cast(float, (unsigned)((unsigned short)s) << 16);
}
// gelu via A&S 7.1.26 erf approx (max abs err 1.5e-7)
DEVI float gelu_f(float x) {
  float z = fabsf(x) * 0.7071067811865476f;
  float t = __builtin_amdgcn_rcpf(1.0f + 0.3275911f * z);
  float p = t * (0.254829592f +
            t * (-0.284496736f +
            t * (1.421413741f +
            t * (-1.453152027f + t * 1.061405429f))));
  float e = exp2f(-z * z * 1.4426950408889634f);
  float er = copysignf(1.0f - p * e, x);
  return 0.5f * x * (1.0f + er);
}

DEVI void gload16(const void* gsrc, void* ldst) {
  __builtin_amdgcn_global_load_lds(
      (const __attribute__((address_space(1))) unsigned*)gsrc,
      (__attribute__((address_space(3))) unsigned*)(ldst), 16, 0, 0);
}

DEVI f32x4 mfma16(bf16x8 a, bf16x8 b, f32x4 c) {
  return __builtin_amdgcn_mfma_f32_16x16x32_bf16(a, b, c, 0, 0, 0);
}
DEVI f32x16 mfma32(bf16x8 a, bf16x8 b, f32x16 c) {
  return __builtin_amdgcn_mfma_f32_32x32x16_bf16(a, b, c, 0, 0, 0);
}

// ---------------- prep (one launch): bf16 cvt x3, weight transpose x4, rope table ----------
// blocks [0,12288): cvt; [12288,17408): wt_trans; [17408,18432): cos/sin table
__global__ void prep_all_kernel(const float* __restrict__ in_q, const float* __restrict__ in_v,
                                const float* __restrict__ in_u, short* __restrict__ C1,
                                short* __restrict__ C2, short* __restrict__ C3,
                                const float* __restrict__ W0, const float* __restrict__ W1,
                                const float* __restrict__ W2, const float* __restrict__ W3,
                                short* __restrict__ T0, short* __restrict__ T1,
                                short* __restrict__ T2, short* __restrict__ T3,
                                float2* __restrict__ cs) {
  __shared__ float tbuf[32][33];
  const int bid = blockIdx.x;
  const int t = threadIdx.x;
  if (bid < 12288) {
    int which = bid >> 12, blk = bid & 4095;
    const float* in = (which == 0) ? in_q : (which == 1) ? in_v : in_u;
    short* out = (which == 0) ? C1 : (which == 1) ? C2 : C3;
    size_t i = ((size_t)blk * 256 + t) * 8;
    float4 f1 = *reinterpret_cast<const float4*>(in + i);
    float4 f2 = *reinterpret_cast<const float4*>(in + i + 4);
    uint4 pk;
    pk.x = f2bf_bits(f1.x) | (f2bf_bits(f1.y) << 16);
    pk.y = f2bf_bits(f1.z) | (f2bf_bits(f1.w) << 16);
    pk.z = f2bf_bits(f2.x) | (f2bf_bits(f2.y) << 16);
    pk.w = f2bf_bits(f2.z) | (f2bf_bits(f2.w) << 16);
    *reinterpret_cast<uint4*>(out + i) = pk;
  } else if (bid < 17408) {
    int z = (bid - 12288) >> 10, rem = (bid - 12288) & 1023;
    int n0 = (rem & 31) * 32, k0 = (rem >> 5) * 32;
    int tx = t & 31, ty = t >> 5;
    const float* Ws[4] = {W0, W1, W2, W3};
    short* Ts[4] = {T0, T1, T2, T3};
    const float* W = Ws[z];
    short* WT = Ts[z];
#pragma unroll
    for (int i = 0; i < 4; i++) {
      int r = ty + i * 8;
      tbuf[r][tx] = W[(size_t)(k0 + r) * 1024 + n0 + tx];
    }
    __syncthreads();
#pragma unroll
    for (int i = 0; i < 4; i++) {
      int r = ty + i * 8;
      WT[(size_t)(n0 + r) * 1024 + k0 + tx] = f2bf(tbuf[tx][r]);
    }
  } else {
    int base = (bid - 17408) * 256 + t;
#pragma unroll
    for (int j = 0; j < 4; j++) {
      int idx = base + j * 262144;
      int tt = idx >> 9, i = idx & 511;
      float inv = expf((float)i * (-9.210340371976184f / 512.0f));
      float sv, cv;
      sincosf((float)tt * inv, &sv, &cv);
      cs[idx] = make_float2(cv, sv);
    }
  }
}

// ---------------- GEMM core loop macro (128x128 tile, BK=32, 3-buf, vmcnt(4)) -------------
#define GEMM_MAIN_LOOP(A, BT, K)                                                     \
  const int tid = threadIdx.x;                                                       \
  const int wave = tid >> 6, lane = tid & 63;                                        \
  const int lquad = lane >> 4, l15 = lane & 15;                                      \
  const int m0 = blockIdx.x * 128, n0 = blockIdx.y * 128;                            \
  const int wr = wave >> 1, wc = wave & 1;                                           \
  f32x4 acc[4][4] = {};                                                              \
  const int q0 = tid * 16, q1 = tid * 16 + 4096;                                     \
  const int r0 = q0 >> 6, o0 = (q0 & 63) ^ ((r0 & 3) << 4);                          \
  const int r1 = q1 >> 6, o1 = (q1 & 63) ^ ((r1 & 3) << 4);                          \
  const short* a0 = (A) + (size_t)(m0 + r0) * (K) + (o0 >> 1);                       \
  const short* a1 = (A) + (size_t)(m0 + r1) * (K) + (o1 >> 1);                       \
  const short* b0 = (BT) + (size_t)(n0 + r0) * (K) + (o0 >> 1);                      \
  const short* b1 = (BT) + (size_t)(n0 + r1) * (K) + (o1 >> 1);                      \
  G_STAGE(0, 0);                                                                     \
  G_STAGE(1, 32);                                                                    \
  asm volatile("s_waitcnt vmcnt(4)" ::: "memory");                                   \
  __builtin_amdgcn_s_barrier();                                                      \
  const int NT = (K) >> 5;                                                           \
  int cur = 0;                                                                       \
  for (int t = 0; t < NT; t++) {                                                     \
    int nb = cur + 2;                                                                \
    if (nb >= 3) nb -= 3;                                                            \
    G_STAGE(nb, (t + 2 < NT) ? (t + 2) * 32 : 0);                                    \
    __builtin_amdgcn_sched_barrier(0);                                               \
    const char* As_ = smem + cur * 8192;                                             \
    const char* Bs_ = smem + 24576 + cur * 8192;                                     \
    const int ko = lquad * 16;                                                       \
    bf16x8 a[4], b[4];                                                               \
    _Pragma("unroll") for (int f = 0; f < 4; f++) {                                  \
      int ra = wr * 64 + f * 16 + l15;                                               \
      a[f] = *reinterpret_cast<const bf16x8*>(As_ + ra * 64 + (ko ^ ((ra & 3) << 4)));\
      int rb = wc * 64 + f * 16 + l15;                                               \
      b[f] = *reinterpret_cast<const bf16x8*>(Bs_ + rb * 64 + (ko ^ ((rb & 3) << 4)));\
    }                                                                                \
    _Pragma("unroll") for (int mf = 0; mf < 4; mf++)                                 \
      _Pragma("unroll") for (int nf = 0; nf < 4; nf++)                               \
        acc[mf][nf] = mfma16(a[mf], b[nf], acc[mf][nf]);                             \
    asm volatile("s_waitcnt vmcnt(4) lgkmcnt(0)" ::: "memory");                      \
    __builtin_amdgcn_sched_barrier(0);                                               \
    __builtin_amdgcn_s_barrier();                                                    \
    cur = (cur == 2) ? 0 : cur + 1;                                                  \
  }

#define G_STAGE(buf, kt)                     \
  {                                          \
    char* As_ = smem + (buf)*8192;           \
    char* Bs_ = smem + 24576 + (buf)*8192;   \
    gload16(a0 + (kt), As_ + q0);            \
    gload16(a1 + (kt), As_ + q1);            \
    gload16(b0 + (kt), Bs_ + q0);            \
    gload16(b1 + (kt), Bs_ + q1);            \
  }

// ---------------- GEMM: C = epi(A @ W + bias); EPI 0 = f32+bias, 1 = gelu->bf16,
// 3 = gelu->bf16 transposed to vT layout ----------
template <int EPI>
__global__ __launch_bounds__(256, 3) void gemm_kernel(
    const short* __restrict__ A, const short* __restrict__ BT,
    const float* __restrict__ bias, void* __restrict__ Cptr, int M, int N, int K) {
  __shared__ char smem[49152];
  GEMM_MAIN_LOOP(A, BT, K)
#pragma unroll
  for (int mf = 0; mf < 4; mf++) {
#pragma unroll
    for (int nf = 0; nf < 4; nf++) {
      const int mrow = m0 + wr * 64 + mf * 16 + 4 * lquad;
      const int ncol = n0 + wc * 64 + nf * 16 + l15;
      const float bval = bias[ncol];
      if constexpr (EPI == 3) {
        int hh = ncol >> 7, dd = ncol & 127;
        int bb = mrow >> 11, ss = mrow & 2047;
        bf16x4 gv;
#pragma unroll
        for (int r = 0; r < 4; r++) gv[r] = f2bf(gelu_f(acc[mf][nf][r] + bval));
        *reinterpret_cast<bf16x4*>((short*)Cptr + (((size_t)bb * 8 + hh) * 128 + dd) * 2048 + ss) = gv;
      } else if constexpr (EPI == 1) {
#pragma unroll
        for (int r = 0; r < 4; r++)
          ((short*)Cptr)[(size_t)(mrow + r) * N + ncol] = f2bf(gelu_f(acc[mf][nf][r] + bval));
      } else {
#pragma unroll
        for (int r = 0; r < 4; r++)
          ((float*)Cptr)[(size_t)(mrow + r) * N + ncol] = acc[mf][nf][r] + bval;
      }
    }
  }
}

// ---------------- GEMM1 with fused scale-offset + interleaved rotary epilogue --------------
// qout gets QSC pre-scale (exp2 folding downstream). Pair partner lives in adjacent lane.
__global__ __launch_bounds__(256, 3) void gemm_rope_kernel(
    const short* __restrict__ A, const short* __restrict__ BT,
    const float* __restrict__ bias, const float2* __restrict__ cstab,
    const float* __restrict__ qg, const float* __restrict__ qb,
    const float* __restrict__ kg, const float* __restrict__ kb,
    short* __restrict__ qout, short* __restrict__ kout) {
  __shared__ char smem[49152];
  GEMM_MAIN_LOOP(A, BT, Dc)
#pragma unroll
  for (int mf = 0; mf < 4; mf++) {
#pragma unroll
    for (int nf = 0; nf < 4; nf++) {
      const int mrow = m0 + wr * 64 + mf * 16 + 4 * lquad;
      const int ncol = n0 + wc * 64 + nf * 16 + l15;
      const float bval = bias[ncol];
      const int e7 = ncol & 127;
      const float QG = qg[e7], QB = qb[e7], KG = kg[e7], KB = kb[e7];
      const int p = ncol >> 1;
      const float sgn = (ncol & 1) ? 1.0f : -1.0f;
#pragma unroll
      for (int r = 0; r < 4; r++) {
        const int m = mrow + r;
        const int tt = m & 2047;
        float2 cs = cstab[(size_t)tt * 512 + p];
        float g = gelu_f(acc[mf][nf][r] + bval);
        float qv = g * QG + QB, kv = g * KG + KB;
        float pq = __shfl_xor(qv, 1), pk = __shfl_xor(kv, 1);
        qout[(size_t)m * HEc + ncol] = f2bf((qv * cs.x + sgn * pq * cs.y) * QSC);
        kout[(size_t)m * HEc + ncol] = f2bf(kv * cs.x + sgn * pk * cs.y);
      }
    }
  }
}
#undef G_STAGE
#undef GEMM_MAIN_LOOP

// ---------------- attention pass A: rcp[bh][l] = 1 / sum_s exp2(qk) ----------------
// grid 512 = 8 XCD * 4 bh * 16 lblk; 128 L rows/block (32/wave); 32x32x16 MFMA.
__global__ __launch_bounds__(256, 3) void passa_kernel(
    const short* __restrict__ qs, const short* __restrict__ ks,
    float* __restrict__ rcpbuf) {
  __shared__ char smem[49152];  // 3 x 16KB K bufs
  const int bid = blockIdx.x;
  const int xcd = bid & 7, jj = bid >> 3;  // jj 0..63
  const int bh = xcd * 4 + (jj >> 4);
  const int lblk = jj & 15;
  const int b = bh >> 3, h = bh & 7;
  const int l0 = lblk * 128;
  const int tid = threadIdx.x;
  const int wave = tid >> 6, lane = tid & 63;
  const int l31 = lane & 31, lhg = lane >> 5;

  const short* ksrc[4];
  int kq[4];
#pragma unroll
  for (int i = 0; i < 4; i++) {
    int q = i * 4096 + tid * 16;
    kq[i] = q;
    int row = q >> 8, off = (q & 255) ^ ((row & 7) << 4);
    ksrc[i] = ks + (((size_t)b * Sc + row) * Hc + h) * Ec + (off >> 1);
  }

  bf16x8 qf[8];
  {
    const char* qp = (const char*)(qs + (((size_t)b * Lc + l0 + wave * 32 + l31) * Hc + h) * Ec);
#pragma unroll
    for (int kt = 0; kt < 8; kt++)
      qf[kt] = *reinterpret_cast<const bf16x8*>(qp + kt * 32 + 16 * lhg);
  }
  __builtin_amdgcn_sched_barrier(0);

#define STAGE_A(buf, s0)                                  \
  {                                                       \
    char* Kb_ = smem + (buf)*16384;                       \
    gload16(ksrc[0] + (size_t)(s0)*1024, Kb_ + kq[0]);    \
    gload16(ksrc[1] + (size_t)(s0)*1024, Kb_ + kq[1]);    \
    gload16(ksrc[2] + (size_t)(s0)*1024, Kb_ + kq[2]);    \
    gload16(ksrc[3] + (size_t)(s0)*1024, Kb_ + kq[3]);    \
  }

  STAGE_A(0, 0);
  STAGE_A(1, 64);
  asm volatile("s_waitcnt vmcnt(4)" ::: "memory");
  __builtin_amdgcn_s_barrier();
  float ra = 0.f, rb = 0.f, rc = 0.f, rd = 0.f;
  int cur = 0;
  for (int t = 0; t < 32; t++) {
    int nb = cur + 2;
    if (nb >= 3) nb -= 3;
    STAGE_A(nb, (t + 2 < 32) ? (t + 2) * 64 : 0);
    __builtin_amdgcn_sched_barrier(0);
    const char* KB_ = smem + cur * 16384;
    f32x16 d0 = {}, d1 = {};
    __builtin_amdgcn_s_setprio(1);
#pragma unroll
    for (int kt = 0; kt < 8; kt++) {
      int row0 = l31, row1 = 32 + l31;
      bf16x8 k0 = *reinterpret_cast<const bf16x8*>(
          KB_ + row0 * 256 + ((kt * 32 + 16 * lhg) ^ ((row0 & 7) << 4)));
      bf16x8 k1 = *reinterpret_cast<const bf16x8*>(
          KB_ + row1 * 256 + ((kt * 32 + 16 * lhg) ^ ((row1 & 7) << 4)));
      d0 = mfma32(k0, qf[kt], d0);
      d1 = mfma32(k1, qf[kt], d1);
    }
    __builtin_amdgcn_s_setprio(0);
#pragma unroll
    for (int r = 0; r < 16; r += 4) {
      ra += exp2f(d0[r]) + exp2f(d1[r]);
      rb += exp2f(d0[r + 1]) + exp2f(d1[r + 1]);
      rc += exp2f(d0[r + 2]) + exp2f(d1[r + 2]);
      rd += exp2f(d0[r + 3]) + exp2f(d1[r + 3]);
    }
    asm volatile("s_waitcnt vmcnt(4) lgkmcnt(0)" ::: "memory");
    __builtin_amdgcn_sched_barrier(0);
    __builtin_amdgcn_s_barrier();
    cur = (cur == 2) ? 0 : cur + 1;
  }
#undef STAGE_A
  float rs = (ra + rb) + (rc + rd);
  rs += __shfl_xor(rs, 32);
  if (lane < 32)
    rcpbuf[(size_t)bh * Lc + l0 + wave * 32 + l31] = 1.0f / rs;
}

// ---------------- attention pass B ----------------
// grid 512 = 8 XCD * 4 bh * 16 lblk; 128 L rows/block (2x16 per wave); s-tile 32.
// [QK | exp | stores | cvt | PV | STAGE(t+2) | vmcnt(8) | barrier]
__global__ __launch_bounds__(256, 3) void attn_kernel(
    const short* __restrict__ qs, const short* __restrict__ ks,
    const short* __restrict__ vT, const short* __restrict__ up,
    const float* __restrict__ rcpbuf, float* __restrict__ attn_out,
    short* __restrict__ gate) {
  __shared__ char smem[49152];
  const int bid = blockIdx.x;
  const int xcd = bid & 7, jj = bid >> 3;  // jj 0..63
  const int bh = xcd * 4 + (jj >> 4);
  const int lblk = jj & 15;
  const int b = bh >> 3, h = bh & 7;
  const int l0 = lblk * 128;
  const int tid = threadIdx.x;
  const int wave = tid >> 6, lane = tid & 63;
  const int lquad = lane >> 4, l15 = lane & 15;

  const short* ksrc[2];
  int kq[2];
#pragma unroll
  for (int i = 0; i < 2; i++) {
    int q = i * 4096 + tid * 16;
    kq[i] = q;
    int row = q >> 8, off = (q & 255) ^ ((row & 7) << 4);
    ksrc[i] = ks + (((size_t)b * Sc + row) * Hc + h) * Ec + (off >> 1);
  }
  const short* vsrc[2];
  int vq[2];
#pragma unroll
  for (int i = 0; i < 2; i++) {
    int q = i * 4096 + tid * 16;
    vq[i] = q;
    int rv = q >> 6;
    int j = (q >> 4) & 3;
    int c = (j - (rv & 3)) & 3;
    vsrc[i] = vT + ((size_t)bh * UVc + rv) * Sc + (c << 3);
  }

  bf16x8 qf[2][4];
  float rcp[2];
#pragma unroll
  for (int cf = 0; cf < 2; cf++) {
    int lrow = l0 + wave * 32 + cf * 16 + l15;
    const short* qp = qs + (((size_t)b * Lc + lrow) * Hc + h) * Ec;
#pragma unroll
    for (int kt = 0; kt < 4; kt++)
      qf[cf][kt] = *reinterpret_cast<const bf16x8*>(qp + kt * 32 + lquad * 8);
    rcp[cf] = rcpbuf[(size_t)bh * Lc + lrow];
  }
  __builtin_amdgcn_sched_barrier(0);

#define STAGE_B(buf, s0)                                  \
  {                                                       \
    char* Kb_ = smem + (buf)*8192;                        \
    char* Vb_ = smem + 24576 + (buf)*8192;                \
    gload16(ksrc[0] + (size_t)(s0)*1024, Kb_ + kq[0]);    \
    gload16(ksrc[1] + (size_t)(s0)*1024, Kb_ + kq[1]);    \
    gload16(vsrc[0] + (s0), Vb_ + vq[0]);                 \
    gload16(vsrc[1] + (s0), Vb_ + vq[1]);                 \
  }

  STAGE_B(0, 0);
  STAGE_B(1, 32);
  asm volatile("s_waitcnt vmcnt(4)" ::: "memory");
  __builtin_amdgcn_s_barrier();
  f32x4 ctx[8][2] = {};
  int cur = 0;
  for (int t = 0; t < 64; t++) {
    const int s0 = t * 32;
    const char* KB_ = smem + cur * 8192;
    const char* VB_ = smem + 24576 + cur * 8192;
    f32x4 d[2][2] = {};
    __builtin_amdgcn_s_setprio(1);
#pragma unroll
    for (int kt = 0; kt < 4; kt++)
#pragma unroll
      for (int sf = 0; sf < 2; sf++) {
        int row = sf * 16 + l15;
        bf16x8 kf = *reinterpret_cast<const bf16x8*>(
            KB_ + row * 256 + ((kt * 64 + lquad * 16) ^ ((row & 7) << 4)));
        d[sf][0] = mfma16(kf, qf[0][kt], d[sf][0]);
        d[sf][1] = mfma16(kf, qf[1][kt], d[sf][1]);
      }
    __builtin_amdgcn_s_setprio(0);
#pragma unroll
    for (int sf = 0; sf < 2; sf++)
#pragma unroll
      for (int cf = 0; cf < 2; cf++)
#pragma unroll
        for (int r = 0; r < 4; r++)
          d[sf][cf][r] = exp2f(d[sf][cf][r]) * rcp[cf];
#pragma unroll
    for (int cf = 0; cf < 2; cf++) {
      int lrow = l0 + wave * 32 + cf * 16 + l15;
      float* arow = attn_out + ((size_t)bh * Lc + lrow) * Sc + s0 + lquad * 4;
      __builtin_nontemporal_store(d[0][cf], reinterpret_cast<f32x4*>(arow));
      __builtin_nontemporal_store(d[1][cf], reinterpret_cast<f32x4*>(arow + 16));
    }
    bf16x8 pb[2];
#pragma unroll
    for (int cf = 0; cf < 2; cf++)
#pragma unroll
      for (int r = 0; r < 4; r++) {
        pb[cf][r] = f2bf(d[0][cf][r]);
        pb[cf][4 + r] = f2bf(d[1][cf][r]);
      }
    __builtin_amdgcn_s_setprio(1);
#pragma unroll
    for (int df = 0; df < 8; df++) {
      int dd = df * 16 + l15;
      const char* vrow = VB_ + dd * 64;
      int half = (lquad & 1) * 8;
      int clo = ((lquad >> 1) + (dd & 3)) & 3;
      int chi = ((lquad >> 1) + 2 + (dd & 3)) & 3;
      bf16x4 lo = *reinterpret_cast<const bf16x4*>(vrow + clo * 16 + half);
      bf16x4 hi = *reinterpret_cast<const bf16x4*>(vrow + chi * 16 + half);
      bf16x8 vf = __builtin_shufflevector(lo, hi, 0, 1, 2, 3, 4, 5, 6, 7);
      ctx[df][0] = mfma16(vf, pb[0], ctx[df][0]);
      ctx[df][1] = mfma16(vf, pb[1], ctx[df][1]);
    }
    __builtin_amdgcn_s_setprio(0);
    {
      int nb = cur + 2;
      if (nb >= 3) nb -= 3;
      STAGE_B(nb, (t + 2 < 64) ? s0 + 64 : 0);
    }
    asm volatile("s_waitcnt vmcnt(8) lgkmcnt(0)" ::: "memory");
    __builtin_amdgcn_sched_barrier(0);
    __builtin_amdgcn_s_barrier();
    cur = (cur == 2) ? 0 : cur + 1;
  }
#undef STAGE_B

#pragma unroll
  for (int cf = 0; cf < 2; cf++) {
    int lrow = l0 + wave * 32 + cf * 16 + l15;
    size_t base = ((size_t)b * Lc + lrow) * HEc + h * UVc;
    const short* ub = up + base;
    short* gp = gate + base;
#pragma unroll
    for (int df = 0; df < 8; df++) {
      int doff = df * 16 + lquad * 4;
      bf16x4 uv = *reinterpret_cast<const bf16x4*>(ub + doff);
      bf16x4 gv;
#pragma unroll
      for (int r = 0; r < 4; r++)
        gv[r] = f2bf(bf2f(uv[r]) * ctx[df][cf][r]);
      *reinterpret_cast<bf16x4*>(gp + doff) = gv;
    }
  }
}

// ---------------- launch ----------------
extern "C" void kernel_launch(void* const* d_in, const int* in_sizes, int n_in,
                              void* d_out, int out_size, void* d_ws, size_t ws_size,
                              hipStream_t stream) {
  const float* u_in = (const float*)d_in[0];
  const float* qry = (const float*)d_in[1];
  // d_in[2] = keys : unused (use_aff shared qk projection)
  const float* vals = (const float*)d_in[3];
  const float* Wqk = (const float*)d_in[4];
  const float* bqk = (const float*)d_in[5];
  const float* Wv = (const float*)d_in[6];
  const float* bv = (const float*)d_in[7];
  const float* Wu = (const float*)d_in[8];
  const float* bu = (const float*)d_in[9];
  const float* Wo = (const float*)d_in[10];
  const float* bo = (const float*)d_in[11];
  const float* qg = (const float*)d_in[12];
  const float* qb = (const float*)d_in[13];
  const float* kg = (const float*)d_in[14];
  const float* kb = (const float*)d_in[15];

  char* w = (char*)d_ws;
  short* WT0 = (short*)w; w += (size_t)1024 * 1024 * 2;
  short* WT1 = (short*)w; w += (size_t)1024 * 1024 * 2;
  short* WT2 = (short*)w; w += (size_t)1024 * 1024 * 2;
  short* WT3 = (short*)w; w += (size_t)1024 * 1024 * 2;
  float2* cstab = (float2*)w; w += (size_t)2048 * 512 * 8;
  float* rcpb = (float*)w; w += (size_t)32 * 2048 * 4;
  const size_t BUF = (size_t)BLc * HEc * 2;  // 16.78 MB
  short* C1 = (short*)w; w += BUF;   // bf16 queries; reused as gate after gemm1
  short* C2 = (short*)w; w += BUF;   // bf16 values
  short* C3 = (short*)w; w += BUF;   // bf16 u
  short* qbf = (short*)w; w += BUF;
  short* kbf = (short*)w; w += BUF;
  short* vTb = (short*)w; w += BUF;
  short* upb = (short*)w; w += BUF;
  short* gtb = C1;  // C1 dead after gemm_rope

  float* o_out = (float*)d_out;
  float* attn_out = o_out + (size_t)BLc * Dc;

  prep_all_kernel<<<18432, 256, 0, stream>>>(qry, vals, u_in, C1, C2, C3, Wqk, Wv, Wu, Wo,
                                             WT0, WT1, WT2, WT3, cstab);
  gemm_rope_kernel<<<dim3(64, 8), 256, 0, stream>>>(C1, WT0, bqk, cstab, qg, qb, kg, kb,
                                                    qbf, kbf);
  passa_kernel<<<512, 256, 0, stream>>>(qbf, kbf, rcpb);
  gemm_kernel<3><<<dim3(64, 8), 256, 0, stream>>>(C2, WT1, bv, vTb, BLc, HEc, Dc);
  gemm_kernel<1><<<dim3(64, 8), 256, 0, stream>>>(C3, WT2, bu, upb, BLc, HEc, Dc);
  attn_kernel<<<512, 256, 0, stream>>>(qbf, kbf, vTb, upb, rcpb, attn_out, gtb);
  gemm_kernel<0><<<dim3(64, 8), 256, 0, stream>>>(gtb, WT3, bo, o_out, BLc, Dc, HEc);
}

// Round 10
// 364.960 us; speedup vs baseline: 1.1267x; 1.0379x over previous
//
#include <hip/hip_runtime.h>
#include <hip/hip_bf16.h>
#include <math.h>

#define DEVI static __device__ __forceinline__

typedef __attribute__((ext_vector_type(4))) float f32x4;
typedef __attribute__((ext_vector_type(16))) float f32x16;
typedef __attribute__((ext_vector_type(8))) short bf16x8;
typedef __attribute__((ext_vector_type(4))) short bf16x4;

constexpr int Bc = 4, Lc = 2048, Sc = 2048, Dc = 1024, Hc = 8, Ec = 128, UVc = 128;
constexpr int HEc = Hc * Ec;   // 1024
constexpr int BLc = Bc * Lc;   // 8192

// scale * log2(e): folded into q so exp(scale*qk) == exp2(d)
#define QSC (1.44269504088896340f / 11.31370849898476039f)

DEVI unsigned f2bf_bits(float f) {
  unsigned u = __builtin_bit_cast(unsigned, f);
  return (u + 0x7FFFu + ((u >> 16) & 1u)) >> 16;
}
DEVI short f2bf(float f) { return (short)f2bf_bits(f); }
DEVI float bf2f(short s) {
  return __builtin_bit_cast(float, (unsigned)((unsigned short)s) << 16);
}
// gelu via A&S 7.1.26 erf approx (max abs err 1.5e-7)
DEVI float gelu_f(float x) {
  float z = fabsf(x) * 0.7071067811865476f;
  float t = __builtin_amdgcn_rcpf(1.0f + 0.3275911f * z);
  float p = t * (0.254829592f +
            t * (-0.284496736f +
            t * (1.421413741f +
            t * (-1.453152027f + t * 1.061405429f))));
  float e = exp2f(-z * z * 1.4426950408889634f);
  float er = copysignf(1.0f - p * e, x);
  return 0.5f * x * (1.0f + er);
}

DEVI void gload16(const void* gsrc, void* ldst) {
  __builtin_amdgcn_global_load_lds(
      (const __attribute__((address_space(1))) unsigned*)gsrc,
      (__attribute__((address_space(3))) unsigned*)(ldst), 16, 0, 0);
}

DEVI f32x4 mfma16(bf16x8 a, bf16x8 b, f32x4 c) {
  return __builtin_amdgcn_mfma_f32_16x16x32_bf16(a, b, c, 0, 0, 0);
}
DEVI f32x16 mfma32(bf16x8 a, bf16x8 b, f32x16 c) {
  return __builtin_amdgcn_mfma_f32_32x32x16_bf16(a, b, c, 0, 0, 0);
}

// ---------------- prep (one launch): bf16 cvt x3, weight transpose x4, rope table ----------
__global__ void prep_all_kernel(const float* __restrict__ in_q, const float* __restrict__ in_v,
                                const float* __restrict__ in_u, short* __restrict__ C1,
                                short* __restrict__ C2, short* __restrict__ C3,
                                const float* __restrict__ W0, const float* __restrict__ W1,
                                const float* __restrict__ W2, const float* __restrict__ W3,
                                short* __restrict__ T0, short* __restrict__ T1,
                                short* __restrict__ T2, short* __restrict__ T3,
                                float2* __restrict__ cs) {
  __shared__ float tbuf[32][33];
  const int bid = blockIdx.x;
  const int t = threadIdx.x;
  if (bid < 12288) {
    int which = bid >> 12, blk = bid & 4095;
    const float* in = (which == 0) ? in_q : (which == 1) ? in_v : in_u;
    short* out = (which == 0) ? C1 : (which == 1) ? C2 : C3;
    size_t i = ((size_t)blk * 256 + t) * 8;
    float4 f1 = *reinterpret_cast<const float4*>(in + i);
    float4 f2 = *reinterpret_cast<const float4*>(in + i + 4);
    uint4 pk;
    pk.x = f2bf_bits(f1.x) | (f2bf_bits(f1.y) << 16);
    pk.y = f2bf_bits(f1.z) | (f2bf_bits(f1.w) << 16);
    pk.z = f2bf_bits(f2.x) | (f2bf_bits(f2.y) << 16);
    pk.w = f2bf_bits(f2.z) | (f2bf_bits(f2.w) << 16);
    *reinterpret_cast<uint4*>(out + i) = pk;
  } else if (bid < 17408) {
    int z = (bid - 12288) >> 10, rem = (bid - 12288) & 1023;
    int n0 = (rem & 31) * 32, k0 = (rem >> 5) * 32;
    int tx = t & 31, ty = t >> 5;
    const float* Ws[4] = {W0, W1, W2, W3};
    short* Ts[4] = {T0, T1, T2, T3};
    const float* W = Ws[z];
    short* WT = Ts[z];
#pragma unroll
    for (int i = 0; i < 4; i++) {
      int r = ty + i * 8;
      tbuf[r][tx] = W[(size_t)(k0 + r) * 1024 + n0 + tx];
    }
    __syncthreads();
#pragma unroll
    for (int i = 0; i < 4; i++) {
      int r = ty + i * 8;
      WT[(size_t)(n0 + r) * 1024 + k0 + tx] = f2bf(tbuf[tx][r]);
    }
  } else {
    int base = (bid - 17408) * 256 + t;
#pragma unroll
    for (int j = 0; j < 4; j++) {
      int idx = base + j * 262144;
      int tt = idx >> 9, i = idx & 511;
      float inv = expf((float)i * (-9.210340371976184f / 512.0f));
      float sv, cv;
      sincosf((float)tt * inv, &sv, &cv);
      cs[idx] = make_float2(cv, sv);
    }
  }
}

// ---------------- GEMM body (128x128 tile, BK=32, 3-buf, vmcnt(4)); bx flat in [0,512) ----
// EPI: 0 = f32+bias, 1 = gelu->bf16, 2 = rope q/k, 3 = gelu->bf16 transposed to vT layout
template <int EPI>
DEVI void gemm_body(char* smem, int bx,
                    const short* __restrict__ A, const short* __restrict__ BT,
                    const float* __restrict__ bias, void* __restrict__ Cptr, int K, int N,
                    const float2* __restrict__ cstab,
                    const float* __restrict__ qg, const float* __restrict__ qb,
                    const float* __restrict__ kg, const float* __restrict__ kb,
                    short* __restrict__ qout, short* __restrict__ kout) {
  const int tid = threadIdx.x;
  const int wave = tid >> 6, lane = tid & 63;
  const int lquad = lane >> 4, l15 = lane & 15;
  const int m0 = (bx & 63) * 128, n0 = (bx >> 6) * 128;
  const int wr = wave >> 1, wc = wave & 1;
  f32x4 acc[4][4] = {};

  const int q0 = tid * 16, q1 = tid * 16 + 4096;
  const int r0 = q0 >> 6, o0 = (q0 & 63) ^ ((r0 & 3) << 4);
  const int r1 = q1 >> 6, o1 = (q1 & 63) ^ ((r1 & 3) << 4);
  const short* a0 = A + (size_t)(m0 + r0) * K + (o0 >> 1);
  const short* a1 = A + (size_t)(m0 + r1) * K + (o1 >> 1);
  const short* b0 = BT + (size_t)(n0 + r0) * K + (o0 >> 1);
  const short* b1 = BT + (size_t)(n0 + r1) * K + (o1 >> 1);

#define G_STAGE(buf, kt)                     \
  {                                          \
    char* As_ = smem + (buf)*8192;           \
    char* Bs_ = smem + 24576 + (buf)*8192;   \
    gload16(a0 + (kt), As_ + q0);            \
    gload16(a1 + (kt), As_ + q1);            \
    gload16(b0 + (kt), Bs_ + q0);            \
    gload16(b1 + (kt), Bs_ + q1);            \
  }

  G_STAGE(0, 0);
  G_STAGE(1, 32);
  asm volatile("s_waitcnt vmcnt(4)" ::: "memory");
  __builtin_amdgcn_s_barrier();

  const int NT = K >> 5;
  int cur = 0;
  for (int t = 0; t < NT; t++) {
    int nb = cur + 2;
    if (nb >= 3) nb -= 3;
    G_STAGE(nb, (t + 2 < NT) ? (t + 2) * 32 : 0);
    __builtin_amdgcn_sched_barrier(0);
    const char* As_ = smem + cur * 8192;
    const char* Bs_ = smem + 24576 + cur * 8192;
    const int ko = lquad * 16;
    bf16x8 a[4], b[4];
#pragma unroll
    for (int f = 0; f < 4; f++) {
      int ra = wr * 64 + f * 16 + l15;
      a[f] = *reinterpret_cast<const bf16x8*>(As_ + ra * 64 + (ko ^ ((ra & 3) << 4)));
      int rb = wc * 64 + f * 16 + l15;
      b[f] = *reinterpret_cast<const bf16x8*>(Bs_ + rb * 64 + (ko ^ ((rb & 3) << 4)));
    }
#pragma unroll
    for (int mf = 0; mf < 4; mf++)
#pragma unroll
      for (int nf = 0; nf < 4; nf++)
        acc[mf][nf] = mfma16(a[mf], b[nf], acc[mf][nf]);
    asm volatile("s_waitcnt vmcnt(4) lgkmcnt(0)" ::: "memory");
    __builtin_amdgcn_sched_barrier(0);
    __builtin_amdgcn_s_barrier();
    cur = (cur == 2) ? 0 : cur + 1;
  }
#undef G_STAGE

#pragma unroll
  for (int mf = 0; mf < 4; mf++) {
#pragma unroll
    for (int nf = 0; nf < 4; nf++) {
      const int mrow = m0 + wr * 64 + mf * 16 + 4 * lquad;
      const int ncol = n0 + wc * 64 + nf * 16 + l15;
      const float bval = bias[ncol];
      if constexpr (EPI == 2) {
        const int e7 = ncol & 127;
        const float QG = qg[e7], QB = qb[e7], KG = kg[e7], KB = kb[e7];
        const int p = ncol >> 1;
        const float sgn = (ncol & 1) ? 1.0f : -1.0f;
#pragma unroll
        for (int r = 0; r < 4; r++) {
          const int m = mrow + r;
          const int tt = m & 2047;
          float2 cs = cstab[(size_t)tt * 512 + p];
          float g = gelu_f(acc[mf][nf][r] + bval);
          float qv = g * QG + QB, kv = g * KG + KB;
          float pq = __shfl_xor(qv, 1), pk = __shfl_xor(kv, 1);
          qout[(size_t)m * HEc + ncol] = f2bf((qv * cs.x + sgn * pq * cs.y) * QSC);
          kout[(size_t)m * HEc + ncol] = f2bf(kv * cs.x + sgn * pk * cs.y);
        }
      } else if constexpr (EPI == 3) {
        int hh = ncol >> 7, dd = ncol & 127;
        int bb = mrow >> 11, ss = mrow & 2047;
        bf16x4 gv;
#pragma unroll
        for (int r = 0; r < 4; r++) gv[r] = f2bf(gelu_f(acc[mf][nf][r] + bval));
        *reinterpret_cast<bf16x4*>((short*)Cptr + (((size_t)bb * 8 + hh) * 128 + dd) * 2048 + ss) = gv;
      } else if constexpr (EPI == 1) {
#pragma unroll
        for (int r = 0; r < 4; r++)
          ((short*)Cptr)[(size_t)(mrow + r) * N + ncol] = f2bf(gelu_f(acc[mf][nf][r] + bval));
      } else {
#pragma unroll
        for (int r = 0; r < 4; r++)
          ((float*)Cptr)[(size_t)(mrow + r) * N + ncol] = acc[mf][nf][r] + bval;
      }
    }
  }
}

// ---------------- pass A body: rcp[bh][l] = 1 / sum_s exp2(qk); bid in [0,512) --------------
DEVI void passa_body(char* smem, int bid, const short* __restrict__ qs,
                     const short* __restrict__ ks, float* __restrict__ rcpbuf) {
  const int xcd = bid & 7, jj = bid >> 3;
  const int bh = xcd * 4 + (jj >> 4);
  const int lblk = jj & 15;
  const int b = bh >> 3, h = bh & 7;
  const int l0 = lblk * 128;
  const int tid = threadIdx.x;
  const int wave = tid >> 6, lane = tid & 63;
  const int l31 = lane & 31, lhg = lane >> 5;

  const short* ksrc[4];
  int kq[4];
#pragma unroll
  for (int i = 0; i < 4; i++) {
    int q = i * 4096 + tid * 16;
    kq[i] = q;
    int row = q >> 8, off = (q & 255) ^ ((row & 7) << 4);
    ksrc[i] = ks + (((size_t)b * Sc + row) * Hc + h) * Ec + (off >> 1);
  }

  bf16x8 qf[8];
  {
    const char* qp = (const char*)(qs + (((size_t)b * Lc + l0 + wave * 32 + l31) * Hc + h) * Ec);
#pragma unroll
    for (int kt = 0; kt < 8; kt++)
      qf[kt] = *reinterpret_cast<const bf16x8*>(qp + kt * 32 + 16 * lhg);
  }
  __builtin_amdgcn_sched_barrier(0);

#define STAGE_A(buf, s0)                                  \
  {                                                       \
    char* Kb_ = smem + (buf)*16384;                       \
    gload16(ksrc[0] + (size_t)(s0)*1024, Kb_ + kq[0]);    \
    gload16(ksrc[1] + (size_t)(s0)*1024, Kb_ + kq[1]);    \
    gload16(ksrc[2] + (size_t)(s0)*1024, Kb_ + kq[2]);    \
    gload16(ksrc[3] + (size_t)(s0)*1024, Kb_ + kq[3]);    \
  }

  STAGE_A(0, 0);
  STAGE_A(1, 64);
  asm volatile("s_waitcnt vmcnt(4)" ::: "memory");
  __builtin_amdgcn_s_barrier();
  float ra = 0.f, rb = 0.f, rc = 0.f, rd = 0.f;
  int cur = 0;
  for (int t = 0; t < 32; t++) {
    int nb = cur + 2;
    if (nb >= 3) nb -= 3;
    STAGE_A(nb, (t + 2 < 32) ? (t + 2) * 64 : 0);
    __builtin_amdgcn_sched_barrier(0);
    const char* KB_ = smem + cur * 16384;
    f32x16 d0 = {}, d1 = {};
    __builtin_amdgcn_s_setprio(1);
#pragma unroll
    for (int kt = 0; kt < 8; kt++) {
      int row0 = l31, row1 = 32 + l31;
      bf16x8 k0 = *reinterpret_cast<const bf16x8*>(
          KB_ + row0 * 256 + ((kt * 32 + 16 * lhg) ^ ((row0 & 7) << 4)));
      bf16x8 k1 = *reinterpret_cast<const bf16x8*>(
          KB_ + row1 * 256 + ((kt * 32 + 16 * lhg) ^ ((row1 & 7) << 4)));
      d0 = mfma32(k0, qf[kt], d0);
      d1 = mfma32(k1, qf[kt], d1);
    }
    __builtin_amdgcn_s_setprio(0);
#pragma unroll
    for (int r = 0; r < 16; r += 4) {
      ra += exp2f(d0[r]) + exp2f(d1[r]);
      rb += exp2f(d0[r + 1]) + exp2f(d1[r + 1]);
      rc += exp2f(d0[r + 2]) + exp2f(d1[r + 2]);
      rd += exp2f(d0[r + 3]) + exp2f(d1[r + 3]);
    }
    asm volatile("s_waitcnt vmcnt(4) lgkmcnt(0)" ::: "memory");
    __builtin_amdgcn_sched_barrier(0);
    __builtin_amdgcn_s_barrier();
    cur = (cur == 2) ? 0 : cur + 1;
  }
#undef STAGE_A
  float rs = (ra + rb) + (rc + rd);
  rs += __shfl_xor(rs, 32);
  if (lane < 32)
    rcpbuf[(size_t)bh * Lc + l0 + wave * 32 + l31] = 1.0f / rs;
}

// ---------------- mid kernel: passa [0,512) ∥ gemm_v EPI3 [512,1024) ∥ gemm_u EPI1 -------
__global__ __launch_bounds__(256, 3) void mid_kernel(
    const short* __restrict__ qs, const short* __restrict__ ks, float* __restrict__ rcpbuf,
    const short* __restrict__ C2, const short* __restrict__ WT1,
    const float* __restrict__ bv, short* __restrict__ vTb,
    const short* __restrict__ C3, const short* __restrict__ WT2,
    const float* __restrict__ bu, short* __restrict__ upb) {
  __shared__ char smem[49152];
  const int bid = blockIdx.x;
  if (bid < 512) {
    passa_body(smem, bid, qs, ks, rcpbuf);
  } else if (bid < 1024) {
    gemm_body<3>(smem, bid - 512, C2, WT1, bv, vTb, Dc, HEc,
                 nullptr, nullptr, nullptr, nullptr, nullptr, nullptr, nullptr);
  } else {
    gemm_body<1>(smem, bid - 1024, C3, WT2, bu, upb, Dc, HEc,
                 nullptr, nullptr, nullptr, nullptr, nullptr, nullptr, nullptr);
  }
}

// ---------------- standalone GEMM wrappers ----------------
__global__ __launch_bounds__(256, 3) void gemm_rope_kernel(
    const short* __restrict__ A, const short* __restrict__ BT,
    const float* __restrict__ bias, const float2* __restrict__ cstab,
    const float* __restrict__ qg, const float* __restrict__ qb,
    const float* __restrict__ kg, const float* __restrict__ kb,
    short* __restrict__ qout, short* __restrict__ kout) {
  __shared__ char smem[49152];
  gemm_body<2>(smem, blockIdx.x, A, BT, bias, nullptr, Dc, HEc,
               cstab, qg, qb, kg, kb, qout, kout);
}

__global__ __launch_bounds__(256, 3) void gemm_out_kernel(
    const short* __restrict__ A, const short* __restrict__ BT,
    const float* __restrict__ bias, float* __restrict__ C) {
  __shared__ char smem[49152];
  gemm_body<0>(smem, blockIdx.x, A, BT, bias, C, HEc, Dc,
               nullptr, nullptr, nullptr, nullptr, nullptr, nullptr, nullptr);
}

// ---------------- attention pass B ----------------
// grid 512 = 8 XCD * 4 bh * 16 lblk; 128 L rows/block (2x16 per wave); s-tile 32.
// [QK | exp | stores | cvt | PV | STAGE(t+2) | vmcnt(8) | barrier]
__global__ __launch_bounds__(256, 3) void attn_kernel(
    const short* __restrict__ qs, const short* __restrict__ ks,
    const short* __restrict__ vT, const short* __restrict__ up,
    const float* __restrict__ rcpbuf, float* __restrict__ attn_out,
    short* __restrict__ gate) {
  __shared__ char smem[49152];
  const int bid = blockIdx.x;
  const int xcd = bid & 7, jj = bid >> 3;
  const int bh = xcd * 4 + (jj >> 4);
  const int lblk = jj & 15;
  const int b = bh >> 3, h = bh & 7;
  const int l0 = lblk * 128;
  const int tid = threadIdx.x;
  const int wave = tid >> 6, lane = tid & 63;
  const int lquad = lane >> 4, l15 = lane & 15;

  const short* ksrc[2];
  int kq[2];
#pragma unroll
  for (int i = 0; i < 2; i++) {
    int q = i * 4096 + tid * 16;
    kq[i] = q;
    int row = q >> 8, off = (q & 255) ^ ((row & 7) << 4);
    ksrc[i] = ks + (((size_t)b * Sc + row) * Hc + h) * Ec + (off >> 1);
  }
  const short* vsrc[2];
  int vq[2];
#pragma unroll
  for (int i = 0; i < 2; i++) {
    int q = i * 4096 + tid * 16;
    vq[i] = q;
    int rv = q >> 6;
    int j = (q >> 4) & 3;
    int c = (j - (rv & 3)) & 3;
    vsrc[i] = vT + ((size_t)bh * UVc + rv) * Sc + (c << 3);
  }

  bf16x8 qf[2][4];
  float rcp[2];
#pragma unroll
  for (int cf = 0; cf < 2; cf++) {
    int lrow = l0 + wave * 32 + cf * 16 + l15;
    const short* qp = qs + (((size_t)b * Lc + lrow) * Hc + h) * Ec;
#pragma unroll
    for (int kt = 0; kt < 4; kt++)
      qf[cf][kt] = *reinterpret_cast<const bf16x8*>(qp + kt * 32 + lquad * 8);
    rcp[cf] = rcpbuf[(size_t)bh * Lc + lrow];
  }
  __builtin_amdgcn_sched_barrier(0);

#define STAGE_B(buf, s0)                                  \
  {                                                       \
    char* Kb_ = smem + (buf)*8192;                        \
    char* Vb_ = smem + 24576 + (buf)*8192;                \
    gload16(ksrc[0] + (size_t)(s0)*1024, Kb_ + kq[0]);    \
    gload16(ksrc[1] + (size_t)(s0)*1024, Kb_ + kq[1]);    \
    gload16(vsrc[0] + (s0), Vb_ + vq[0]);                 \
    gload16(vsrc[1] + (s0), Vb_ + vq[1]);                 \
  }

  STAGE_B(0, 0);
  STAGE_B(1, 32);
  asm volatile("s_waitcnt vmcnt(4)" ::: "memory");
  __builtin_amdgcn_s_barrier();
  f32x4 ctx[8][2] = {};
  int cur = 0;
  for (int t = 0; t < 64; t++) {
    const int s0 = t * 32;
    const char* KB_ = smem + cur * 8192;
    const char* VB_ = smem + 24576 + cur * 8192;
    f32x4 d[2][2] = {};
    __builtin_amdgcn_s_setprio(1);
#pragma unroll
    for (int kt = 0; kt < 4; kt++)
#pragma unroll
      for (int sf = 0; sf < 2; sf++) {
        int row = sf * 16 + l15;
        bf16x8 kf = *reinterpret_cast<const bf16x8*>(
            KB_ + row * 256 + ((kt * 64 + lquad * 16) ^ ((row & 7) << 4)));
        d[sf][0] = mfma16(kf, qf[0][kt], d[sf][0]);
        d[sf][1] = mfma16(kf, qf[1][kt], d[sf][1]);
      }
    __builtin_amdgcn_s_setprio(0);
#pragma unroll
    for (int sf = 0; sf < 2; sf++)
#pragma unroll
      for (int cf = 0; cf < 2; cf++)
#pragma unroll
        for (int r = 0; r < 4; r++)
          d[sf][cf][r] = exp2f(d[sf][cf][r]) * rcp[cf];
#pragma unroll
    for (int cf = 0; cf < 2; cf++) {
      int lrow = l0 + wave * 32 + cf * 16 + l15;
      float* arow = attn_out + ((size_t)bh * Lc + lrow) * Sc + s0 + lquad * 4;
      __builtin_nontemporal_store(d[0][cf], reinterpret_cast<f32x4*>(arow));
      __builtin_nontemporal_store(d[1][cf], reinterpret_cast<f32x4*>(arow + 16));
    }
    bf16x8 pb[2];
#pragma unroll
    for (int cf = 0; cf < 2; cf++)
#pragma unroll
      for (int r = 0; r < 4; r++) {
        pb[cf][r] = f2bf(d[0][cf][r]);
        pb[cf][4 + r] = f2bf(d[1][cf][r]);
      }
    __builtin_amdgcn_s_setprio(1);
#pragma unroll
    for (int df = 0; df < 8; df++) {
      int dd = df * 16 + l15;
      const char* vrow = VB_ + dd * 64;
      int half = (lquad & 1) * 8;
      int clo = ((lquad >> 1) + (dd & 3)) & 3;
      int chi = ((lquad >> 1) + 2 + (dd & 3)) & 3;
      bf16x4 lo = *reinterpret_cast<const bf16x4*>(vrow + clo * 16 + half);
      bf16x4 hi = *reinterpret_cast<const bf16x4*>(vrow + chi * 16 + half);
      bf16x8 vf = __builtin_shufflevector(lo, hi, 0, 1, 2, 3, 4, 5, 6, 7);
      ctx[df][0] = mfma16(vf, pb[0], ctx[df][0]);
      ctx[df][1] = mfma16(vf, pb[1], ctx[df][1]);
    }
    __builtin_amdgcn_s_setprio(0);
    {
      int nb = cur + 2;
      if (nb >= 3) nb -= 3;
      STAGE_B(nb, (t + 2 < 64) ? s0 + 64 : 0);
    }
    asm volatile("s_waitcnt vmcnt(8) lgkmcnt(0)" ::: "memory");
    __builtin_amdgcn_sched_barrier(0);
    __builtin_amdgcn_s_barrier();
    cur = (cur == 2) ? 0 : cur + 1;
  }
#undef STAGE_B

#pragma unroll
  for (int cf = 0; cf < 2; cf++) {
    int lrow = l0 + wave * 32 + cf * 16 + l15;
    size_t base = ((size_t)b * Lc + lrow) * HEc + h * UVc;
    const short* ub = up + base;
    short* gp = gate + base;
#pragma unroll
    for (int df = 0; df < 8; df++) {
      int doff = df * 16 + lquad * 4;
      bf16x4 uv = *reinterpret_cast<const bf16x4*>(ub + doff);
      bf16x4 gv;
#pragma unroll
      for (int r = 0; r < 4; r++)
        gv[r] = f2bf(bf2f(uv[r]) * ctx[df][cf][r]);
      *reinterpret_cast<bf16x4*>(gp + doff) = gv;
    }
  }
}

// ---------------- launch ----------------
extern "C" void kernel_launch(void* const* d_in, const int* in_sizes, int n_in,
                              void* d_out, int out_size, void* d_ws, size_t ws_size,
                              hipStream_t stream) {
  const float* u_in = (const float*)d_in[0];
  const float* qry = (const float*)d_in[1];
  // d_in[2] = keys : unused (use_aff shared qk projection)
  const float* vals = (const float*)d_in[3];
  const float* Wqk = (const float*)d_in[4];
  const float* bqk = (const float*)d_in[5];
  const float* Wv = (const float*)d_in[6];
  const float* bv = (const float*)d_in[7];
  const float* Wu = (const float*)d_in[8];
  const float* bu = (const float*)d_in[9];
  const float* Wo = (const float*)d_in[10];
  const float* bo = (const float*)d_in[11];
  const float* qg = (const float*)d_in[12];
  const float* qb = (const float*)d_in[13];
  const float* kg = (const float*)d_in[14];
  const float* kb = (const float*)d_in[15];

  char* w = (char*)d_ws;
  short* WT0 = (short*)w; w += (size_t)1024 * 1024 * 2;
  short* WT1 = (short*)w; w += (size_t)1024 * 1024 * 2;
  short* WT2 = (short*)w; w += (size_t)1024 * 1024 * 2;
  short* WT3 = (short*)w; w += (size_t)1024 * 1024 * 2;
  float2* cstab = (float2*)w; w += (size_t)2048 * 512 * 8;
  float* rcpb = (float*)w; w += (size_t)32 * 2048 * 4;
  const size_t BUF = (size_t)BLc * HEc * 2;  // 16.78 MB
  short* C1 = (short*)w; w += BUF;   // bf16 queries; reused as gate after gemm_rope
  short* C2 = (short*)w; w += BUF;   // bf16 values
  short* C3 = (short*)w; w += BUF;   // bf16 u
  short* qbf = (short*)w; w += BUF;
  short* kbf = (short*)w; w += BUF;
  short* vTb = (short*)w; w += BUF;
  short* upb = (short*)w; w += BUF;
  short* gtb = C1;  // C1 dead after gemm_rope

  float* o_out = (float*)d_out;
  float* attn_out = o_out + (size_t)BLc * Dc;

  prep_all_kernel<<<18432, 256, 0, stream>>>(qry, vals, u_in, C1, C2, C3, Wqk, Wv, Wu, Wo,
                                             WT0, WT1, WT2, WT3, cstab);
  gemm_rope_kernel<<<512, 256, 0, stream>>>(C1, WT0, bqk, cstab, qg, qb, kg, kb, qbf, kbf);
  mid_kernel<<<1536, 256, 0, stream>>>(qbf, kbf, rcpb, C2, WT1, bv, vTb, C3, WT2, bu, upb);
  attn_kernel<<<512, 256, 0, stream>>>(qbf, kbf, vTb, upb, rcpb, attn_out, gtb);
  gemm_out_kernel<<<512, 256, 0, stream>>>(gtb, WT3, bo, o_out);
}

// Round 11
// 361.705 us; speedup vs baseline: 1.1368x; 1.0090x over previous
//
#include <hip/hip_runtime.h>
#include <hip/hip_bf16.h>
#include <math.h>

#define DEVI static __device__ __forceinline__

typedef __attribute__((ext_vector_type(4))) float f32x4;
typedef __attribute__((ext_vector_type(16))) float f32x16;
typedef __attribute__((ext_vector_type(8))) short bf16x8;
typedef __attribute__((ext_vector_type(4))) short bf16x4;

constexpr int Bc = 4, Lc = 2048, Sc = 2048, Dc = 1024, Hc = 8, Ec = 128, UVc = 128;
constexpr int HEc = Hc * Ec;   // 1024
constexpr int BLc = Bc * Lc;   // 8192

// scale * log2(e): folded into q so exp(scale*qk) == exp2(d)
#define QSC (1.44269504088896340f / 11.31370849898476039f)

DEVI unsigned f2bf_bits(float f) {
  unsigned u = __builtin_bit_cast(unsigned, f);
  return (u + 0x7FFFu + ((u >> 16) & 1u)) >> 16;
}
DEVI short f2bf(float f) { return (short)f2bf_bits(f); }
DEVI float bf2f(short s) {
  return __builtin_bit_cast(float, (unsigned)((unsigned short)s) << 16);
}
// gelu via A&S 7.1.26 erf approx (max abs err 1.5e-7)
DEVI float gelu_f(float x) {
  float z = fabsf(x) * 0.7071067811865476f;
  float t = __builtin_amdgcn_rcpf(1.0f + 0.3275911f * z);
  float p = t * (0.254829592f +
            t * (-0.284496736f +
            t * (1.421413741f +
            t * (-1.453152027f + t * 1.061405429f))));
  float e = exp2f(-z * z * 1.4426950408889634f);
  float er = copysignf(1.0f - p * e, x);
  return 0.5f * x * (1.0f + er);
}

DEVI void gload16(const void* gsrc, void* ldst) {
  __builtin_amdgcn_global_load_lds(
      (const __attribute__((address_space(1))) unsigned*)gsrc,
      (__attribute__((address_space(3))) unsigned*)(ldst), 16, 0, 0);
}

DEVI f32x4 mfma16(bf16x8 a, bf16x8 b, f32x4 c) {
  return __builtin_amdgcn_mfma_f32_16x16x32_bf16(a, b, c, 0, 0, 0);
}
DEVI f32x16 mfma32(bf16x8 a, bf16x8 b, f32x16 c) {
  return __builtin_amdgcn_mfma_f32_32x32x16_bf16(a, b, c, 0, 0, 0);
}

// ---------------- prep bodies ----------------
DEVI void cvt_body(int blk, int t, const float* __restrict__ in, short* __restrict__ out) {
  size_t i = ((size_t)blk * 256 + t) * 8;
  float4 f1 = *reinterpret_cast<const float4*>(in + i);
  float4 f2 = *reinterpret_cast<const float4*>(in + i + 4);
  uint4 pk;
  pk.x = f2bf_bits(f1.x) | (f2bf_bits(f1.y) << 16);
  pk.y = f2bf_bits(f1.z) | (f2bf_bits(f1.w) << 16);
  pk.z = f2bf_bits(f2.x) | (f2bf_bits(f2.y) << 16);
  pk.w = f2bf_bits(f2.z) | (f2bf_bits(f2.w) << 16);
  *reinterpret_cast<uint4*>(out + i) = pk;
}

DEVI void wt_body(float (*tbuf)[33], int rem, int t, const float* __restrict__ W,
                  short* __restrict__ WT) {
  int n0 = (rem & 31) * 32, k0 = (rem >> 5) * 32;
  int tx = t & 31, ty = t >> 5;
#pragma unroll
  for (int i = 0; i < 4; i++) {
    int r = ty + i * 8;
    tbuf[r][tx] = W[(size_t)(k0 + r) * 1024 + n0 + tx];
  }
  __syncthreads();
#pragma unroll
  for (int i = 0; i < 4; i++) {
    int r = ty + i * 8;
    WT[(size_t)(n0 + r) * 1024 + k0 + tx] = f2bf(tbuf[tx][r]);
  }
}

DEVI void cstab_body(int blk, int t, float2* __restrict__ cs) {
  int base = blk * 256 + t;
#pragma unroll
  for (int j = 0; j < 4; j++) {
    int idx = base + j * 262144;
    int tt = idx >> 9, i = idx & 511;
    float inv = expf((float)i * (-9.210340371976184f / 512.0f));
    float sv, cv;
    sincosf((float)tt * inv, &sv, &cv);
    cs[idx] = make_float2(cv, sv);
  }
}

// ---------------- GEMM body (128x128 tile, BK=32, 3-buf, vmcnt(4)); bx flat in [0,512) ----
// EPI: 0 = f32+bias, 1 = gelu->bf16, 2 = rope q/k, 3 = gelu->bf16 transposed to vT layout
template <int EPI>
DEVI void gemm_body(char* smem, int bx,
                    const short* __restrict__ A, const short* __restrict__ BT,
                    const float* __restrict__ bias, void* __restrict__ Cptr, int K, int N,
                    const float2* __restrict__ cstab,
                    const float* __restrict__ qg, const float* __restrict__ qb,
                    const float* __restrict__ kg, const float* __restrict__ kb,
                    short* __restrict__ qout, short* __restrict__ kout) {
  const int tid = threadIdx.x;
  const int wave = tid >> 6, lane = tid & 63;
  const int lquad = lane >> 4, l15 = lane & 15;
  const int m0 = (bx & 63) * 128, n0 = (bx >> 6) * 128;
  const int wr = wave >> 1, wc = wave & 1;
  f32x4 acc[4][4] = {};

  const int q0 = tid * 16, q1 = tid * 16 + 4096;
  const int r0 = q0 >> 6, o0 = (q0 & 63) ^ ((r0 & 3) << 4);
  const int r1 = q1 >> 6, o1 = (q1 & 63) ^ ((r1 & 3) << 4);
  const short* a0 = A + (size_t)(m0 + r0) * K + (o0 >> 1);
  const short* a1 = A + (size_t)(m0 + r1) * K + (o1 >> 1);
  const short* b0 = BT + (size_t)(n0 + r0) * K + (o0 >> 1);
  const short* b1 = BT + (size_t)(n0 + r1) * K + (o1 >> 1);

#define G_STAGE(buf, kt)                     \
  {                                          \
    char* As_ = smem + (buf)*8192;           \
    char* Bs_ = smem + 24576 + (buf)*8192;   \
    gload16(a0 + (kt), As_ + q0);            \
    gload16(a1 + (kt), As_ + q1);            \
    gload16(b0 + (kt), Bs_ + q0);            \
    gload16(b1 + (kt), Bs_ + q1);            \
  }

  G_STAGE(0, 0);
  G_STAGE(1, 32);
  asm volatile("s_waitcnt vmcnt(4)" ::: "memory");
  __builtin_amdgcn_s_barrier();

  const int NT = K >> 5;
  int cur = 0;
  for (int t = 0; t < NT; t++) {
    int nb = cur + 2;
    if (nb >= 3) nb -= 3;
    G_STAGE(nb, (t + 2 < NT) ? (t + 2) * 32 : 0);
    __builtin_amdgcn_sched_barrier(0);
    const char* As_ = smem + cur * 8192;
    const char* Bs_ = smem + 24576 + cur * 8192;
    const int ko = lquad * 16;
    bf16x8 a[4], b[4];
#pragma unroll
    for (int f = 0; f < 4; f++) {
      int ra = wr * 64 + f * 16 + l15;
      a[f] = *reinterpret_cast<const bf16x8*>(As_ + ra * 64 + (ko ^ ((ra & 3) << 4)));
      int rb = wc * 64 + f * 16 + l15;
      b[f] = *reinterpret_cast<const bf16x8*>(Bs_ + rb * 64 + (ko ^ ((rb & 3) << 4)));
    }
#pragma unroll
    for (int mf = 0; mf < 4; mf++)
#pragma unroll
      for (int nf = 0; nf < 4; nf++)
        acc[mf][nf] = mfma16(a[mf], b[nf], acc[mf][nf]);
    asm volatile("s_waitcnt vmcnt(4) lgkmcnt(0)" ::: "memory");
    __builtin_amdgcn_sched_barrier(0);
    __builtin_amdgcn_s_barrier();
    cur = (cur == 2) ? 0 : cur + 1;
  }
#undef G_STAGE

#pragma unroll
  for (int mf = 0; mf < 4; mf++) {
#pragma unroll
    for (int nf = 0; nf < 4; nf++) {
      const int mrow = m0 + wr * 64 + mf * 16 + 4 * lquad;
      const int ncol = n0 + wc * 64 + nf * 16 + l15;
      const float bval = bias[ncol];
      if constexpr (EPI == 2) {
        const int e7 = ncol & 127;
        const float QG = qg[e7], QB = qb[e7], KG = kg[e7], KB = kb[e7];
        const int p = ncol >> 1;
        const float sgn = (ncol & 1) ? 1.0f : -1.0f;
#pragma unroll
        for (int r = 0; r < 4; r++) {
          const int m = mrow + r;
          const int tt = m & 2047;
          float2 cs = cstab[(size_t)tt * 512 + p];
          float g = gelu_f(acc[mf][nf][r] + bval);
          float qv = g * QG + QB, kv = g * KG + KB;
          float pq = __shfl_xor(qv, 1), pk = __shfl_xor(kv, 1);
          qout[(size_t)m * HEc + ncol] = f2bf((qv * cs.x + sgn * pq * cs.y) * QSC);
          kout[(size_t)m * HEc + ncol] = f2bf(kv * cs.x + sgn * pk * cs.y);
        }
      } else if constexpr (EPI == 3) {
        int hh = ncol >> 7, dd = ncol & 127;
        int bb = mrow >> 11, ss = mrow & 2047;
        bf16x4 gv;
#pragma unroll
        for (int r = 0; r < 4; r++) gv[r] = f2bf(gelu_f(acc[mf][nf][r] + bval));
        *reinterpret_cast<bf16x4*>((short*)Cptr + (((size_t)bb * 8 + hh) * 128 + dd) * 2048 + ss) = gv;
      } else if constexpr (EPI == 1) {
#pragma unroll
        for (int r = 0; r < 4; r++)
          ((short*)Cptr)[(size_t)(mrow + r) * N + ncol] = f2bf(gelu_f(acc[mf][nf][r] + bval));
      } else {
#pragma unroll
        for (int r = 0; r < 4; r++)
          ((float*)Cptr)[(size_t)(mrow + r) * N + ncol] = acc[mf][nf][r] + bval;
      }
    }
  }
}

// ---------------- pass A body: rcp[bh][l] = 1 / sum_s exp2(qk); bid in [0,512) --------------
DEVI void passa_body(char* smem, int bid, const short* __restrict__ qs,
                     const short* __restrict__ ks, float* __restrict__ rcpbuf) {
  const int xcd = bid & 7, jj = bid >> 3;
  const int bh = xcd * 4 + (jj >> 4);
  const int lblk = jj & 15;
  const int b = bh >> 3, h = bh & 7;
  const int l0 = lblk * 128;
  const int tid = threadIdx.x;
  const int wave = tid >> 6, lane = tid & 63;
  const int l31 = lane & 31, lhg = lane >> 5;

  const short* ksrc[4];
  int kq[4];
#pragma unroll
  for (int i = 0; i < 4; i++) {
    int q = i * 4096 + tid * 16;
    kq[i] = q;
    int row = q >> 8, off = (q & 255) ^ ((row & 7) << 4);
    ksrc[i] = ks + (((size_t)b * Sc + row) * Hc + h) * Ec + (off >> 1);
  }

  bf16x8 qf[8];
  {
    const char* qp = (const char*)(qs + (((size_t)b * Lc + l0 + wave * 32 + l31) * Hc + h) * Ec);
#pragma unroll
    for (int kt = 0; kt < 8; kt++)
      qf[kt] = *reinterpret_cast<const bf16x8*>(qp + kt * 32 + 16 * lhg);
  }
  __builtin_amdgcn_sched_barrier(0);

#define STAGE_A(buf, s0)                                  \
  {                                                       \
    char* Kb_ = smem + (buf)*16384;                       \
    gload16(ksrc[0] + (size_t)(s0)*1024, Kb_ + kq[0]);    \
    gload16(ksrc[1] + (size_t)(s0)*1024, Kb_ + kq[1]);    \
    gload16(ksrc[2] + (size_t)(s0)*1024, Kb_ + kq[2]);    \
    gload16(ksrc[3] + (size_t)(s0)*1024, Kb_ + kq[3]);    \
  }

  STAGE_A(0, 0);
  STAGE_A(1, 64);
  asm volatile("s_waitcnt vmcnt(4)" ::: "memory");
  __builtin_amdgcn_s_barrier();
  float ra = 0.f, rb = 0.f, rc = 0.f, rd = 0.f;
  int cur = 0;
  for (int t = 0; t < 32; t++) {
    int nb = cur + 2;
    if (nb >= 3) nb -= 3;
    STAGE_A(nb, (t + 2 < 32) ? (t + 2) * 64 : 0);
    __builtin_amdgcn_sched_barrier(0);
    const char* KB_ = smem + cur * 16384;
    f32x16 d0 = {}, d1 = {};
    __builtin_amdgcn_s_setprio(1);
#pragma unroll
    for (int kt = 0; kt < 8; kt++) {
      int row0 = l31, row1 = 32 + l31;
      bf16x8 k0 = *reinterpret_cast<const bf16x8*>(
          KB_ + row0 * 256 + ((kt * 32 + 16 * lhg) ^ ((row0 & 7) << 4)));
      bf16x8 k1 = *reinterpret_cast<const bf16x8*>(
          KB_ + row1 * 256 + ((kt * 32 + 16 * lhg) ^ ((row1 & 7) << 4)));
      d0 = mfma32(k0, qf[kt], d0);
      d1 = mfma32(k1, qf[kt], d1);
    }
    __builtin_amdgcn_s_setprio(0);
#pragma unroll
    for (int r = 0; r < 16; r += 4) {
      ra += exp2f(d0[r]) + exp2f(d1[r]);
      rb += exp2f(d0[r + 1]) + exp2f(d1[r + 1]);
      rc += exp2f(d0[r + 2]) + exp2f(d1[r + 2]);
      rd += exp2f(d0[r + 3]) + exp2f(d1[r + 3]);
    }
    asm volatile("s_waitcnt vmcnt(4) lgkmcnt(0)" ::: "memory");
    __builtin_amdgcn_sched_barrier(0);
    __builtin_amdgcn_s_barrier();
    cur = (cur == 2) ? 0 : cur + 1;
  }
#undef STAGE_A
  float rs = (ra + rb) + (rc + rd);
  rs += __shfl_xor(rs, 32);
  if (lane < 32)
    rcpbuf[(size_t)bh * Lc + l0 + wave * 32 + l31] = 1.0f / rs;
}

// ---------------- K1: prep1 — cvt q [0,4096), WT0 [4096,5120), cstab [5120,6144) ----------
__global__ void prep1_kernel(const float* __restrict__ qry, short* __restrict__ C1,
                             const float* __restrict__ Wqk, short* __restrict__ WT0,
                             float2* __restrict__ cs) {
  __shared__ float tbuf[32][33];
  const int bid = blockIdx.x, t = threadIdx.x;
  if (bid < 4096) {
    cvt_body(bid, t, qry, C1);
  } else if (bid < 5120) {
    wt_body(tbuf, bid - 4096, t, Wqk, WT0);
  } else {
    cstab_body(bid - 5120, t, cs);
  }
}

// ---------------- K2: gemm_rope [0,512) ∥ prep2 (cvt v/u, WT1/2/3) [512,11776) -----------
__global__ __launch_bounds__(256, 3) void rope_prep2_kernel(
    const short* __restrict__ C1, const short* __restrict__ WT0,
    const float* __restrict__ bqk, const float2* __restrict__ cstab,
    const float* __restrict__ qg, const float* __restrict__ qb,
    const float* __restrict__ kg, const float* __restrict__ kb,
    short* __restrict__ qbf, short* __restrict__ kbf,
    const float* __restrict__ vals, short* __restrict__ C2,
    const float* __restrict__ u_in, short* __restrict__ C3,
    const float* __restrict__ Wv, short* __restrict__ WT1,
    const float* __restrict__ Wu, short* __restrict__ WT2,
    const float* __restrict__ Wo, short* __restrict__ WT3) {
  __shared__ char smem[49152];
  const int bid = blockIdx.x, t = threadIdx.x;
  if (bid < 512) {
    gemm_body<2>(smem, bid, C1, WT0, bqk, nullptr, Dc, HEc,
                 cstab, qg, qb, kg, kb, qbf, kbf);
  } else if (bid < 4608) {
    cvt_body(bid - 512, t, vals, C2);
  } else if (bid < 8704) {
    cvt_body(bid - 4608, t, u_in, C3);
  } else if (bid < 9728) {
    wt_body((float(*)[33])smem, bid - 8704, t, Wv, WT1);
  } else if (bid < 10752) {
    wt_body((float(*)[33])smem, bid - 9728, t, Wu, WT2);
  } else {
    wt_body((float(*)[33])smem, bid - 10752, t, Wo, WT3);
  }
}

// ---------------- mid kernel: passa [0,512) ∥ gemm_v EPI3 [512,1024) ∥ gemm_u EPI1 -------
__global__ __launch_bounds__(256, 3) void mid_kernel(
    const short* __restrict__ qs, const short* __restrict__ ks, float* __restrict__ rcpbuf,
    const short* __restrict__ C2, const short* __restrict__ WT1,
    const float* __restrict__ bv, short* __restrict__ vTb,
    const short* __restrict__ C3, const short* __restrict__ WT2,
    const float* __restrict__ bu, short* __restrict__ upb) {
  __shared__ char smem[49152];
  const int bid = blockIdx.x;
  if (bid < 512) {
    passa_body(smem, bid, qs, ks, rcpbuf);
  } else if (bid < 1024) {
    gemm_body<3>(smem, bid - 512, C2, WT1, bv, vTb, Dc, HEc,
                 nullptr, nullptr, nullptr, nullptr, nullptr, nullptr, nullptr);
  } else {
    gemm_body<1>(smem, bid - 1024, C3, WT2, bu, upb, Dc, HEc,
                 nullptr, nullptr, nullptr, nullptr, nullptr, nullptr, nullptr);
  }
}

// ---------------- standalone output GEMM ----------------
__global__ __launch_bounds__(256, 3) void gemm_out_kernel(
    const short* __restrict__ A, const short* __restrict__ BT,
    const float* __restrict__ bias, float* __restrict__ C) {
  __shared__ char smem[49152];
  gemm_body<0>(smem, blockIdx.x, A, BT, bias, C, HEc, Dc,
               nullptr, nullptr, nullptr, nullptr, nullptr, nullptr, nullptr);
}

// ---------------- attention pass B ----------------
// grid 512 = 8 XCD * 4 bh * 16 lblk; 128 L rows/block (2x16 per wave); s-tile 32.
// [QK | exp | stores | cvt | PV | STAGE(t+2) | vmcnt(8) | barrier]
__global__ __launch_bounds__(256, 3) void attn_kernel(
    const short* __restrict__ qs, const short* __restrict__ ks,
    const short* __restrict__ vT, const short* __restrict__ up,
    const float* __restrict__ rcpbuf, float* __restrict__ attn_out,
    short* __restrict__ gate) {
  __shared__ char smem[49152];
  const int bid = blockIdx.x;
  const int xcd = bid & 7, jj = bid >> 3;
  const int bh = xcd * 4 + (jj >> 4);
  const int lblk = jj & 15;
  const int b = bh >> 3, h = bh & 7;
  const int l0 = lblk * 128;
  const int tid = threadIdx.x;
  const int wave = tid >> 6, lane = tid & 63;
  const int lquad = lane >> 4, l15 = lane & 15;

  const short* ksrc[2];
  int kq[2];
#pragma unroll
  for (int i = 0; i < 2; i++) {
    int q = i * 4096 + tid * 16;
    kq[i] = q;
    int row = q >> 8, off = (q & 255) ^ ((row & 7) << 4);
    ksrc[i] = ks + (((size_t)b * Sc + row) * Hc + h) * Ec + (off >> 1);
  }
  const short* vsrc[2];
  int vq[2];
#pragma unroll
  for (int i = 0; i < 2; i++) {
    int q = i * 4096 + tid * 16;
    vq[i] = q;
    int rv = q >> 6;
    int j = (q >> 4) & 3;
    int c = (j - (rv & 3)) & 3;
    vsrc[i] = vT + ((size_t)bh * UVc + rv) * Sc + (c << 3);
  }

  bf16x8 qf[2][4];
  float rcp[2];
#pragma unroll
  for (int cf = 0; cf < 2; cf++) {
    int lrow = l0 + wave * 32 + cf * 16 + l15;
    const short* qp = qs + (((size_t)b * Lc + lrow) * Hc + h) * Ec;
#pragma unroll
    for (int kt = 0; kt < 4; kt++)
      qf[cf][kt] = *reinterpret_cast<const bf16x8*>(qp + kt * 32 + lquad * 8);
    rcp[cf] = rcpbuf[(size_t)bh * Lc + lrow];
  }
  __builtin_amdgcn_sched_barrier(0);

#define STAGE_B(buf, s0)                                  \
  {                                                       \
    char* Kb_ = smem + (buf)*8192;                        \
    char* Vb_ = smem + 24576 + (buf)*8192;                \
    gload16(ksrc[0] + (size_t)(s0)*1024, Kb_ + kq[0]);    \
    gload16(ksrc[1] + (size_t)(s0)*1024, Kb_ + kq[1]);    \
    gload16(vsrc[0] + (s0), Vb_ + vq[0]);                 \
    gload16(vsrc[1] + (s0), Vb_ + vq[1]);                 \
  }

  STAGE_B(0, 0);
  STAGE_B(1, 32);
  asm volatile("s_waitcnt vmcnt(4)" ::: "memory");
  __builtin_amdgcn_s_barrier();
  f32x4 ctx[8][2] = {};
  int cur = 0;
  for (int t = 0; t < 64; t++) {
    const int s0 = t * 32;
    const char* KB_ = smem + cur * 8192;
    const char* VB_ = smem + 24576 + cur * 8192;
    f32x4 d[2][2] = {};
    __builtin_amdgcn_s_setprio(1);
#pragma unroll
    for (int kt = 0; kt < 4; kt++)
#pragma unroll
      for (int sf = 0; sf < 2; sf++) {
        int row = sf * 16 + l15;
        bf16x8 kf = *reinterpret_cast<const bf16x8*>(
            KB_ + row * 256 + ((kt * 64 + lquad * 16) ^ ((row & 7) << 4)));
        d[sf][0] = mfma16(kf, qf[0][kt], d[sf][0]);
        d[sf][1] = mfma16(kf, qf[1][kt], d[sf][1]);
      }
    __builtin_amdgcn_s_setprio(0);
#pragma unroll
    for (int sf = 0; sf < 2; sf++)
#pragma unroll
      for (int cf = 0; cf < 2; cf++)
#pragma unroll
        for (int r = 0; r < 4; r++)
          d[sf][cf][r] = exp2f(d[sf][cf][r]) * rcp[cf];
#pragma unroll
    for (int cf = 0; cf < 2; cf++) {
      int lrow = l0 + wave * 32 + cf * 16 + l15;
      float* arow = attn_out + ((size_t)bh * Lc + lrow) * Sc + s0 + lquad * 4;
      __builtin_nontemporal_store(d[0][cf], reinterpret_cast<f32x4*>(arow));
      __builtin_nontemporal_store(d[1][cf], reinterpret_cast<f32x4*>(arow + 16));
    }
    bf16x8 pb[2];
#pragma unroll
    for (int cf = 0; cf < 2; cf++)
#pragma unroll
      for (int r = 0; r < 4; r++) {
        pb[cf][r] = f2bf(d[0][cf][r]);
        pb[cf][4 + r] = f2bf(d[1][cf][r]);
      }
    __builtin_amdgcn_s_setprio(1);
#pragma unroll
    for (int df = 0; df < 8; df++) {
      int dd = df * 16 + l15;
      const char* vrow = VB_ + dd * 64;
      int half = (lquad & 1) * 8;
      int clo = ((lquad >> 1) + (dd & 3)) & 3;
      int chi = ((lquad >> 1) + 2 + (dd & 3)) & 3;
      bf16x4 lo = *reinterpret_cast<const bf16x4*>(vrow + clo * 16 + half);
      bf16x4 hi = *reinterpret_cast<const bf16x4*>(vrow + chi * 16 + half);
      bf16x8 vf = __builtin_shufflevector(lo, hi, 0, 1, 2, 3, 4, 5, 6, 7);
      ctx[df][0] = mfma16(vf, pb[0], ctx[df][0]);
      ctx[df][1] = mfma16(vf, pb[1], ctx[df][1]);
    }
    __builtin_amdgcn_s_setprio(0);
    {
      int nb = cur + 2;
      if (nb >= 3) nb -= 3;
      STAGE_B(nb, (t + 2 < 64) ? s0 + 64 : 0);
    }
    asm volatile("s_waitcnt vmcnt(8) lgkmcnt(0)" ::: "memory");
    __builtin_amdgcn_sched_barrier(0);
    __builtin_amdgcn_s_barrier();
    cur = (cur == 2) ? 0 : cur + 1;
  }
#undef STAGE_B

#pragma unroll
  for (int cf = 0; cf < 2; cf++) {
    int lrow = l0 + wave * 32 + cf * 16 + l15;
    size_t base = ((size_t)b * Lc + lrow) * HEc + h * UVc;
    const short* ub = up + base;
    short* gp = gate + base;
#pragma unroll
    for (int df = 0; df < 8; df++) {
      int doff = df * 16 + lquad * 4;
      bf16x4 uv = *reinterpret_cast<const bf16x4*>(ub + doff);
      bf16x4 gv;
#pragma unroll
      for (int r = 0; r < 4; r++)
        gv[r] = f2bf(bf2f(uv[r]) * ctx[df][cf][r]);
      *reinterpret_cast<bf16x4*>(gp + doff) = gv;
    }
  }
}

// ---------------- launch ----------------
extern "C" void kernel_launch(void* const* d_in, const int* in_sizes, int n_in,
                              void* d_out, int out_size, void* d_ws, size_t ws_size,
                              hipStream_t stream) {
  const float* u_in = (const float*)d_in[0];
  const float* qry = (const float*)d_in[1];
  // d_in[2] = keys : unused (use_aff shared qk projection)
  const float* vals = (const float*)d_in[3];
  const float* Wqk = (const float*)d_in[4];
  const float* bqk = (const float*)d_in[5];
  const float* Wv = (const float*)d_in[6];
  const float* bv = (const float*)d_in[7];
  const float* Wu = (const float*)d_in[8];
  const float* bu = (const float*)d_in[9];
  const float* Wo = (const float*)d_in[10];
  const float* bo = (const float*)d_in[11];
  const float* qg = (const float*)d_in[12];
  const float* qb = (const float*)d_in[13];
  const float* kg = (const float*)d_in[14];
  const float* kb = (const float*)d_in[15];

  char* w = (char*)d_ws;
  short* WT0 = (short*)w; w += (size_t)1024 * 1024 * 2;
  short* WT1 = (short*)w; w += (size_t)1024 * 1024 * 2;
  short* WT2 = (short*)w; w += (size_t)1024 * 1024 * 2;
  short* WT3 = (short*)w; w += (size_t)1024 * 1024 * 2;
  float2* cstab = (float2*)w; w += (size_t)2048 * 512 * 8;
  float* rcpb = (float*)w; w += (size_t)32 * 2048 * 4;
  const size_t BUF = (size_t)BLc * HEc * 2;  // 16.78 MB
  short* C1 = (short*)w; w += BUF;   // bf16 queries; reused as gate after gemm_rope
  short* C2 = (short*)w; w += BUF;   // bf16 values
  short* C3 = (short*)w; w += BUF;   // bf16 u
  short* qbf = (short*)w; w += BUF;
  short* kbf = (short*)w; w += BUF;
  short* vTb = (short*)w; w += BUF;
  short* upb = (short*)w; w += BUF;
  short* gtb = C1;  // C1 dead after rope_prep2's gemm

  float* o_out = (float*)d_out;
  float* attn_out = o_out + (size_t)BLc * Dc;

  prep1_kernel<<<6144, 256, 0, stream>>>(qry, C1, Wqk, WT0, cstab);
  rope_prep2_kernel<<<11776, 256, 0, stream>>>(C1, WT0, bqk, cstab, qg, qb, kg, kb,
                                               qbf, kbf, vals, C2, u_in, C3,
                                               Wv, WT1, Wu, WT2, Wo, WT3);
  mid_kernel<<<1536, 256, 0, stream>>>(qbf, kbf, rcpb, C2, WT1, bv, vTb, C3, WT2, bu, upb);
  attn_kernel<<<512, 256, 0, stream>>>(qbf, kbf, vTb, upb, rcpb, attn_out, gtb);
  gemm_out_kernel<<<512, 256, 0, stream>>>(gtb, WT3, bo, o_out);
}